// Round 5
// baseline (12591.668 us; speedup 1.0000x reference)
//
#include <hip/hip_runtime.h>
#include <hip/hip_bf16.h>

#define GN 65536
#define GE 131072
#define GB 2048

typedef __attribute__((ext_vector_type(8))) short short8;
typedef __attribute__((ext_vector_type(4))) float floatx4;

static __device__ __forceinline__ float sigm(float x) { return 1.0f / (1.0f + __expf(-x)); }
static __device__ __forceinline__ float bf2f(unsigned short u) {
    union { unsigned int i; float f; } v; v.i = ((unsigned int)u) << 16; return v.f;
}
static __device__ __forceinline__ int geti(const void* p, long long i, int f64) {
    return f64 ? (int)((const long long*)p)[i] : ((const int*)p)[i];
}

// Per-tensor float dtype detector. Scans `nhalf` halfwords (= element count,
// safe for both widths). flag=1 -> read as f32, 0 -> read as bf16.
//   full-f32: low mantissa halves interp as huge/NaN bf16s -> anyHuge
//   bf16-rounded f32: all even halfwords (low mantissa) == 0 -> orEven==0
//   true bf16: neither
__global__ void k_dtype(const unsigned short* __restrict__ p, int nhalf, int* __restrict__ flag) {
    __shared__ unsigned int sAny[256], sOr[256];
    unsigned int any = 0, orEven = 0;
    for (int i = threadIdx.x; i < nhalf; i += 256) {
        const unsigned short u = p[i];
        const float a = fabsf(bf2f(u));
        if (!(a <= 1e6f)) any = 1u;
        if ((i & 1) == 0) orEven |= u;
    }
    sAny[threadIdx.x] = any; sOr[threadIdx.x] = orEven;
    __syncthreads();
    for (int s = 128; s > 0; s >>= 1) {
        if (threadIdx.x < s) {
            sAny[threadIdx.x] |= sAny[threadIdx.x + s];
            sOr[threadIdx.x]  |= sOr[threadIdx.x + s];
        }
        __syncthreads();
    }
    if (threadIdx.x == 0) *flag = (sAny[0] || sOr[0] == 0u) ? 1 : 0;
}

// int64 detector: all odd 32-bit words zero -> int64 storage
__global__ void k_i64(const unsigned int* __restrict__ p, long long nwords, int* __restrict__ flag) {
    __shared__ unsigned int s[256];
    unsigned int acc = 0;
    for (long long w = 1 + 2 * (long long)threadIdx.x; w < nwords; w += 512) acc |= p[w];
    s[threadIdx.x] = acc;
    __syncthreads();
    for (int st = 128; st > 0; st >>= 1) {
        if (threadIdx.x < st) s[threadIdx.x] |= s[threadIdx.x + st];
        __syncthreads();
    }
    if (threadIdx.x == 0) *flag = (s[0] == 0u) ? 1 : 0;
}

__global__ void k_cvt_f32(const void* __restrict__ src, float* __restrict__ dst,
                          int n, const int* __restrict__ flag) {
    int i = blockIdx.x * 256 + threadIdx.x;
    if (i >= n) return;
    dst[i] = (*flag) ? ((const float*)src)[i] : bf2f(((const unsigned short*)src)[i]);
}

__global__ void k_cvt_bf16(const void* __restrict__ src, __hip_bfloat16* __restrict__ dst,
                           int n, const int* __restrict__ flag) {
    int i = blockIdx.x * 256 + threadIdx.x;
    if (i >= n) return;
    if (*flag) dst[i] = __float2bfloat16(((const float*)src)[i]);
    else ((unsigned short*)dst)[i] = ((const unsigned short*)src)[i];
}

__global__ void k_counts(const void* __restrict__ eidx, const int* __restrict__ fi64,
                         float* __restrict__ counts, int E_) {
    int e = blockIdx.x * 256 + threadIdx.x;
    if (e < E_) atomicAdd(&counts[geti(eidx, (long long)E_ + e, *fi64)], 1.0f);
}

__global__ void k_rowptr(const void* __restrict__ gi, const int* __restrict__ fi64,
                         int* __restrict__ rowptr, int N_, int B_) {
    int g = blockIdx.x * 256 + threadIdx.x;
    if (g > B_) return;
    const int f64 = *fi64;
    int lo = 0, hi = N_;
    while (lo < hi) { int mid = (lo + hi) >> 1; if (geti(gi, mid, f64) < g) lo = mid + 1; else hi = mid; }
    rowptr[g] = lo;
}

// lin0: out = relu(nf @ lin0_w + b), nf read polymorphically
__global__ __launch_bounds__(256) void k_lin0(const void* __restrict__ nf_raw,
                                              const float* __restrict__ w,
                                              const float* __restrict__ b,
                                              float* __restrict__ out,
                                              const int* __restrict__ flag) {
    const int ln = threadIdx.x >> 6;
    const int d = threadIdx.x & 63;
    const int n = blockIdx.x * 4 + ln;
    const int isf32 = *flag;
    __shared__ float s_nf[4][76];
    const size_t base = (size_t)n * 75;
    s_nf[ln][d] = isf32 ? ((const float*)nf_raw)[base + d] : bf2f(((const unsigned short*)nf_raw)[base + d]);
    if (d < 11) s_nf[ln][64 + d] = isf32 ? ((const float*)nf_raw)[base + 64 + d]
                                         : bf2f(((const unsigned short*)nf_raw)[base + 64 + d]);
    __syncthreads();
    float acc = b[d];
    #pragma unroll
    for (int i = 0; i < 75; ++i) acc += s_nf[ln][i] * w[i * 64 + d];
    out[(size_t)n * 64 + d] = fmaxf(acc, 0.0f);
}

// h1 = relu(ef @ w1 + b1) -> bf16
__global__ __launch_bounds__(256) void k1_h1(const void* __restrict__ ef_raw,
                                             const float* __restrict__ w1,
                                             const float* __restrict__ b1,
                                             __hip_bfloat16* __restrict__ h1,
                                             const int* __restrict__ flag) {
    const int le = threadIdx.x >> 7;
    const int j = threadIdx.x & 127;
    const int e = blockIdx.x * 2 + le;
    const int isf32 = *flag;
    __shared__ float efs[2][16];
    if (j < 16) {
        const size_t idx = (size_t)e * 16 + j;
        efs[le][j] = isf32 ? ((const float*)ef_raw)[idx] : bf2f(((const unsigned short*)ef_raw)[idx]);
    }
    __syncthreads();
    float acc = b1[j];
    #pragma unroll
    for (int i = 0; i < 16; ++i) acc += efs[le][i] * w1[i * 128 + j];
    h1[(size_t)e * 128 + j] = __float2bfloat16(fmaxf(acc, 0.0f));
}

// W = h1 @ w2 + b2 : MFMA 16x16x32 bf16, 128x128 tile (check-verified on device)
__global__ __launch_bounds__(256) void k2_wgemm(const __hip_bfloat16* __restrict__ h1,
                                                const __hip_bfloat16* __restrict__ w2,
                                                const float* __restrict__ b2,
                                                __hip_bfloat16* __restrict__ W, int e_base) {
    __shared__ __hip_bfloat16 As[128][72];
    __shared__ __hip_bfloat16 Bs[128][72];
    const int tid = threadIdx.x;
    const int le0 = blockIdx.x * 128;
    const int ge0 = e_base + le0;
    const int n0 = blockIdx.y * 128;
    const int wave = tid >> 6, lane = tid & 63;
    const int wm = (wave >> 1) * 64, wn = (wave & 1) * 64;
    const int lr = lane & 15, quad = lane >> 4;
    floatx4 acc[4][4] = {};
    for (int kst = 0; kst < 2; ++kst) {
        const int kb = kst * 64;
        #pragma unroll
        for (int i = 0; i < 4; ++i) {
            int chunk = i * 256 + tid;
            int r = chunk >> 3, c = (chunk & 7) * 8;
            *(int4*)(&As[r][c]) = *(const int4*)(h1 + (size_t)(ge0 + r) * 128 + kb + c);
        }
        #pragma unroll
        for (int i = 0; i < 4; ++i) {
            int chunk = i * 256 + tid;
            int k = chunk >> 4, c = (chunk & 15) * 8;
            int4 v = *(const int4*)(w2 + (size_t)(kb + k) * 4096 + n0 + c);
            const __hip_bfloat16* pv = (const __hip_bfloat16*)&v;
            #pragma unroll
            for (int jj = 0; jj < 8; ++jj) Bs[c + jj][k] = pv[jj];
        }
        __syncthreads();
        #pragma unroll
        for (int ks = 0; ks < 64; ks += 32) {
            short8 af[4], bfr[4];
            #pragma unroll
            for (int mt = 0; mt < 4; ++mt)
                af[mt] = *(const short8*)(&As[wm + mt * 16 + lr][ks + quad * 8]);
            #pragma unroll
            for (int nt = 0; nt < 4; ++nt)
                bfr[nt] = *(const short8*)(&Bs[wn + nt * 16 + lr][ks + quad * 8]);
            #pragma unroll
            for (int mt = 0; mt < 4; ++mt)
                #pragma unroll
                for (int nt = 0; nt < 4; ++nt)
                    acc[mt][nt] = __builtin_amdgcn_mfma_f32_16x16x32_bf16(af[mt], bfr[nt], acc[mt][nt], 0, 0, 0);
        }
        __syncthreads();
    }
    #pragma unroll
    for (int mt = 0; mt < 4; ++mt)
        #pragma unroll
        for (int nt = 0; nt < 4; ++nt) {
            const int col = n0 + wn + nt * 16 + lr;
            const float bias = b2[col];
            #pragma unroll
            for (int r = 0; r < 4; ++r) {
                const int row = le0 + wm + mt * 16 + quad * 4 + r;
                W[(size_t)row * 4096 + col] = __float2bfloat16(acc[mt][nt][r] + bias);
            }
        }
}

// self-check on 8 rows with varied residues mod 128
__global__ void k_check(const unsigned short* __restrict__ Wb,
                        const __hip_bfloat16* __restrict__ h1,
                        const float* __restrict__ w2f, const float* __restrict__ b2,
                        int e_base, int EC, int* __restrict__ flag2) {
    const int i = blockIdx.x * 256 + threadIdx.x;
    const int se = i >> 12, n = i & 4095;
    const int blk = EC >> 3;
    const int le = se * blk + ((se * 1777 + 123) & (blk - 1));
    const size_t ge = (size_t)(e_base + le);
    float ref = b2[n];
    for (int k = 0; k < 128; ++k)
        ref += __bfloat162float(h1[ge * 128 + k]) * w2f[(size_t)k * 4096 + n];
    const float got = bf2f(Wb[(size_t)le * 4096 + n]);
    if (fabsf(got - ref) > 0.03f) *flag2 = 1;
}

__global__ __launch_bounds__(256) void k_repair(__hip_bfloat16* __restrict__ Wb,
                                                const __hip_bfloat16* __restrict__ h1,
                                                const float* __restrict__ w2f,
                                                const float* __restrict__ b2,
                                                int e_base, const int* __restrict__ flag2) {
    if (*flag2 == 0) return;
    __shared__ float As[64][128];
    const int tid = threadIdx.x;
    const int et = blockIdx.x;
    const int c = blockIdx.y * 256 + tid;
    #pragma unroll
    for (int i = 0; i < 32; ++i) {
        int idx = tid * 32 + i;
        int r = idx >> 7, k = idx & 127;
        As[r][k] = __bfloat162float(h1[(size_t)(e_base + et * 64 + r) * 128 + k]);
    }
    __syncthreads();
    float acc[64];
    const float bias = b2[c];
    #pragma unroll
    for (int r = 0; r < 64; ++r) acc[r] = bias;
    for (int k = 0; k < 128; k += 4) {
        const float b0 = w2f[(size_t)(k + 0) * 4096 + c];
        const float b1 = w2f[(size_t)(k + 1) * 4096 + c];
        const float b2v = w2f[(size_t)(k + 2) * 4096 + c];
        const float b3 = w2f[(size_t)(k + 3) * 4096 + c];
        #pragma unroll
        for (int r = 0; r < 64; ++r) {
            float4 a = *(const float4*)&As[r][k];
            acc[r] = fmaf(a.x, b0, fmaf(a.y, b1, fmaf(a.z, b2v, fmaf(a.w, b3, acc[r]))));
        }
    }
    #pragma unroll
    for (int r = 0; r < 64; ++r)
        Wb[(size_t)(et * 64 + r) * 4096 + c] = __float2bfloat16(acc[r]);
}

// msg[e,f] = sum_d out[src[e],d] * W[e,d,f]; atomicAdd into agg[dst[e],f]
__global__ __launch_bounds__(256) void k3_dumb(const __hip_bfloat16* __restrict__ W,
                                               const float* __restrict__ out,
                                               const void* __restrict__ eidx,
                                               const int* __restrict__ fi64,
                                               float* __restrict__ agg,
                                               int e_limit, int e_base) {
    const long long gid = (long long)blockIdx.x * 256 + threadIdx.x;
    const int el = (int)(gid >> 6);
    const int f = (int)(gid & 63);
    const int e = e_base + el;
    if (e >= e_limit) return;
    const int f64 = *fi64;
    const int s = geti(eidx, e, f64);
    const int d = geti(eidx, (long long)GE + e, f64);
    const __hip_bfloat16* We = W + (size_t)el * 4096;
    const float* o = out + (size_t)s * 64;
    float acc = 0.f;
    #pragma unroll 8
    for (int d0 = 0; d0 < 64; ++d0) acc += o[d0] * __bfloat162float(We[d0 * 64 + f]);
    atomicAdd(&agg[(size_t)d * 64 + f], acc);
}

__global__ __launch_bounds__(256) void k4_gru(const float* __restrict__ agg,
                                              const float* __restrict__ counts,
                                              const float* __restrict__ cbias,
                                              const float* __restrict__ w_ih,
                                              const float* __restrict__ w_hh,
                                              const float* __restrict__ b_ih,
                                              const float* __restrict__ b_hh,
                                              float* __restrict__ out) {
    const int ln = threadIdx.x >> 6;
    const int d = threadIdx.x & 63;
    const int n = blockIdx.x * 4 + ln;
    __shared__ float sm[4][64], sh[4][64];
    const float cnt = fmaxf(counts[n], 1.0f);
    const float m = fmaxf(agg[(size_t)n * 64 + d] / cnt + cbias[d], 0.0f);
    const float h = out[(size_t)n * 64 + d];
    sm[ln][d] = m; sh[ln][d] = h;
    __syncthreads();
    float aih[3], ahh[3];
    #pragma unroll
    for (int g = 0; g < 3; ++g) { aih[g] = b_ih[g * 64 + d]; ahh[g] = b_hh[g * 64 + d]; }
    for (int k4 = 0; k4 < 64; k4 += 4) {
        float4 vih[3], vhh[3];
        #pragma unroll
        for (int g = 0; g < 3; ++g) {
            vih[g] = *(const float4*)(w_ih + (size_t)(g * 64 + d) * 64 + k4);
            vhh[g] = *(const float4*)(w_hh + (size_t)(g * 64 + d) * 64 + k4);
        }
        #pragma unroll
        for (int j = 0; j < 4; ++j) {
            const float mk = sm[ln][k4 + j];
            const float hk = sh[ln][k4 + j];
            #pragma unroll
            for (int g = 0; g < 3; ++g) {
                aih[g] += mk * ((const float*)&vih[g])[j];
                ahh[g] += hk * ((const float*)&vhh[g])[j];
            }
        }
    }
    const float r = sigm(aih[0] + ahh[0]);
    const float z = sigm(aih[1] + ahh[1]);
    const float nn = tanhf(aih[2] + r * ahh[2]);
    out[(size_t)n * 64 + d] = (1.0f - z) * nn + z * h;
}

__global__ __launch_bounds__(256) void k5_lstm(float* __restrict__ qstar,
                                               float* __restrict__ hs, float* __restrict__ cs,
                                               const float* __restrict__ w_ih,
                                               const float* __restrict__ w_hh,
                                               const float* __restrict__ b_ih,
                                               const float* __restrict__ b_hh) {
    const int g = blockIdx.x;
    const int j = threadIdx.x;
    __shared__ float qs[128], hv[64], gates[256];
    if (j < 128) qs[j] = qstar[(size_t)g * 128 + j];
    else if (j < 192) hv[j - 128] = hs[(size_t)g * 64 + (j - 128)];
    __syncthreads();
    float acc = b_ih[j] + b_hh[j];
    for (int k4 = 0; k4 < 128; k4 += 4) {
        float4 v = *(const float4*)(w_ih + (size_t)j * 128 + k4);
        const float* pv = (const float*)&v;
        #pragma unroll
        for (int t = 0; t < 4; ++t) acc += qs[k4 + t] * pv[t];
    }
    for (int k4 = 0; k4 < 64; k4 += 4) {
        float4 v = *(const float4*)(w_hh + (size_t)j * 64 + k4);
        const float* pv = (const float*)&v;
        #pragma unroll
        for (int t = 0; t < 4; ++t) acc += hv[k4 + t] * pv[t];
    }
    gates[j] = acc;
    __syncthreads();
    if (j < 64) {
        const float ig = sigm(gates[j]);
        const float fg = sigm(gates[64 + j]);
        const float gg = tanhf(gates[128 + j]);
        const float og = sigm(gates[192 + j]);
        const float c = fg * cs[(size_t)g * 64 + j] + ig * gg;
        const float h = og * tanhf(c);
        cs[(size_t)g * 64 + j] = c;
        hs[(size_t)g * 64 + j] = h;
        qstar[(size_t)g * 128 + j] = h;
    }
}

// attention: block per graph, LDS reductions, chunked online softmax
__global__ __launch_bounds__(64) void k5_attn_d(const float* __restrict__ out,
                                                const float* __restrict__ hs,
                                                const int* __restrict__ rowptr,
                                                float* __restrict__ qstar) {
    const int g = blockIdx.x, t = threadIdx.x;
    __shared__ float sq[64], sa[64], red[64];
    __shared__ float s_m, s_scale, s_S;
    sq[t] = hs[(size_t)g * 64 + t];
    if (t == 0) { s_m = -3.4e38f; s_S = 0.f; s_scale = 1.f; }
    __syncthreads();
    const int start = rowptr[g], end = rowptr[g + 1];
    float racc = 0.f;
    for (int c0 = start; c0 < end; c0 += 64) {
        const int n = c0 + t;
        float et = -3.4e38f;
        if (n < end) {
            float p = 0.f;
            for (int d0 = 0; d0 < 64; ++d0) p += sq[d0] * out[(size_t)n * 64 + d0];
            et = p;
        }
        red[t] = et;
        __syncthreads();
        for (int st = 32; st > 0; st >>= 1) {
            if (t < st) red[t] = fmaxf(red[t], red[t + st]);
            __syncthreads();
        }
        const float newm = fmaxf(s_m, red[0]);
        __syncthreads();
        const float a = (n < end) ? __expf(et - newm) : 0.f;
        sa[t] = a; red[t] = a;
        __syncthreads();
        for (int st = 32; st > 0; st >>= 1) {
            if (t < st) red[t] += red[t + st];
            __syncthreads();
        }
        if (t == 0) {
            const float sc = __expf(s_m - newm);
            s_S = s_S * sc + red[0];
            s_scale = sc;
            s_m = newm;
        }
        __syncthreads();
        racc *= s_scale;
        const int lim = min(64, end - c0);
        for (int tt = 0; tt < lim; ++tt)
            racc += sa[tt] * out[(size_t)(c0 + tt) * 64 + t];
        __syncthreads();
    }
    qstar[(size_t)g * 128 + 64 + t] = racc / (s_S + 1e-16f);
}

// final: pack q_star then feat_map into FLOAT32 d_out (reference output dtype)
__global__ void k_out(const float* __restrict__ qstar, const float* __restrict__ outb,
                      float* __restrict__ dst, int nq, int nfeat, int out_n) {
    int i = blockIdx.x * 256 + threadIdx.x;
    if (i >= out_n) return;
    float v = 0.0f;
    if (i < nq) v = qstar[i];
    else if (i - nq < nfeat) v = outb[i - nq];
    dst[i] = v;
}

extern "C" void kernel_launch(void* const* d_in, const int* in_sizes, int n_in,
                              void* d_out, int out_size, void* d_ws, size_t ws_size,
                              hipStream_t stream) {
    constexpr int N = GN, E = GE, B = GB;

    char* ws = (char*)d_ws;
    size_t off = 0;
    auto alloc = [&](size_t bytes) { size_t o = off; off = (off + bytes + 255) & ~(size_t)255; return o; };

    int*   fl     = (int*)  (ws + alloc(19 * 4));   // per-tensor float flags (1=f32)
    int*   flagE  = (int*)  (ws + alloc(256));      // edge_index int64?
    int*   flagG  = (int*)  (ws + alloc(256));      // graph_index int64?
    int*   flag2  = (int*)  (ws + alloc(256));      // GEMM check failed
    float* counts = (float*)(ws + alloc((size_t)N * 4));
    int*   rowptr = (int*)  (ws + alloc((size_t)(B + 1) * 4));
    float* outbuf = (float*)(ws + alloc((size_t)N * 64 * 4));
    float* agg    = (float*)(ws + alloc((size_t)N * 64 * 4));
    float* qstar  = (float*)(ws + alloc((size_t)B * 128 * 4));
    float* hsb    = (float*)(ws + alloc((size_t)B * 64 * 4));
    float* csb    = (float*)(ws + alloc((size_t)B * 64 * 4));
    __hip_bfloat16* h1   = (__hip_bfloat16*)(ws + alloc((size_t)E * 128 * 2));
    __hip_bfloat16* w2bf = (__hip_bfloat16*)(ws + alloc((size_t)128 * 4096 * 2));

    const int fidx[15]  = {4, 5, 6, 7, 8, 9, 10, 11, 12, 13, 14, 15, 16, 17, 18};
    const int fsize[15] = {75 * 64, 64, 16 * 128, 128, 128 * 4096, 4096, 64,
                           192 * 64, 192 * 64, 192, 192, 256 * 128, 256 * 64, 256, 256};
    float* F[19] = {};
    for (int t = 0; t < 15; ++t) F[fidx[t]] = (float*)(ws + alloc((size_t)fsize[t] * 4));

    const size_t off_W = off;
    __hip_bfloat16* Wbuf = (__hip_bfloat16*)(ws + off_W);
    int EC = E;
    while (EC > 256 && off_W + (size_t)EC * 4096 * 2 > ws_size) EC >>= 1;
    const bool full = (EC == E);

    // per-tensor dtype detection
    k_dtype<<<1, 256, 0, stream>>>((const unsigned short*)d_in[0], N * 75, fl + 0);
    k_dtype<<<1, 256, 0, stream>>>((const unsigned short*)d_in[1], E * 16, fl + 1);
    for (int t = 0; t < 15; ++t)
        k_dtype<<<1, 256, 0, stream>>>((const unsigned short*)d_in[fidx[t]], fsize[t], fl + fidx[t]);
    k_i64<<<1, 256, 0, stream>>>((const unsigned int*)d_in[2], (long long)2 * E, flagE);
    k_i64<<<1, 256, 0, stream>>>((const unsigned int*)d_in[3], (long long)N, flagG);
    hipMemsetAsync(flag2, 0, 4, stream);

    for (int t = 0; t < 15; ++t) {
        int n = fsize[t];
        k_cvt_f32<<<(n + 255) / 256, 256, 0, stream>>>(d_in[fidx[t]], F[fidx[t]], n, fl + fidx[t]);
    }
    k_cvt_bf16<<<(128 * 4096 + 255) / 256, 256, 0, stream>>>(d_in[8], w2bf, 128 * 4096, fl + 8);

    hipMemsetAsync(counts, 0, (size_t)N * 4, stream);
    hipMemsetAsync(qstar, 0, (size_t)B * 128 * 4, stream);
    hipMemsetAsync(hsb, 0, (size_t)B * 64 * 4, stream);
    hipMemsetAsync(csb, 0, (size_t)B * 64 * 4, stream);

    k_counts<<<E / 256, 256, 0, stream>>>(d_in[2], flagE, counts, E);
    k_rowptr<<<(B + 1 + 255) / 256, 256, 0, stream>>>(d_in[3], flagG, rowptr, N, B);
    k_lin0<<<N / 4, 256, 0, stream>>>(d_in[0], F[4], F[5], outbuf, fl + 0);
    k1_h1<<<E / 2, 256, 0, stream>>>(d_in[1], F[6], F[7], h1, fl + 1);

    auto gen_W = [&](int c, int ec) {
        dim3 g2(ec / 128, 32);
        k2_wgemm<<<g2, 256, 0, stream>>>(h1, w2bf, F[9], Wbuf, c);
        k_check<<<8 * 4096 / 256, 256, 0, stream>>>((const unsigned short*)Wbuf, h1,
                                                    F[8], F[9], c, ec, flag2);
        dim3 gr(ec / 64, 16);
        k_repair<<<gr, 256, 0, stream>>>(Wbuf, h1, F[8], F[9], c, flag2);
    };

    if (full) gen_W(0, E);
    for (int it = 0; it < 3; ++it) {
        hipMemsetAsync(agg, 0, (size_t)N * 64 * 4, stream);
        if (full) {
            k3_dumb<<<E / 4, 256, 0, stream>>>(Wbuf, outbuf, d_in[2], flagE, agg, E, 0);
        } else {
            for (int c = 0; c < E; c += EC) {
                gen_W(c, EC);
                k3_dumb<<<EC / 4, 256, 0, stream>>>(Wbuf, outbuf, d_in[2], flagE, agg, c + EC, c);
            }
        }
        k4_gru<<<N / 4, 256, 0, stream>>>(agg, counts, F[10], F[11], F[12], F[13], F[14], outbuf);
    }
    for (int t = 0; t < 3; ++t) {
        k5_lstm<<<B, 256, 0, stream>>>(qstar, hsb, csb, F[15], F[16], F[17], F[18]);
        k5_attn_d<<<B, 64, 0, stream>>>(outbuf, hsb, rowptr, qstar);
    }
    k_out<<<(out_size + 255) / 256, 256, 0, stream>>>(qstar, outbuf, (float*)d_out,
                                                      B * 128, N * 64, out_size);
}

// Round 6
// 6141.836 us; speedup vs baseline: 2.0501x; 2.0501x over previous
//
#include <hip/hip_runtime.h>
#include <hip/hip_bf16.h>

#define GN 65536
#define GE 131072
#define GB 2048

typedef __attribute__((ext_vector_type(8))) short short8;
typedef __attribute__((ext_vector_type(4))) float floatx4;

static __device__ __forceinline__ float sigm(float x) { return 1.0f / (1.0f + __expf(-x)); }
static __device__ __forceinline__ float bf2f(unsigned short u) {
    union { unsigned int i; float f; } v; v.i = ((unsigned int)u) << 16; return v.f;
}
static __device__ __forceinline__ int geti(const void* p, long long i, int f64) {
    return f64 ? (int)((const long long*)p)[i] : ((const int*)p)[i];
}

// Per-tensor float dtype detector, SAMPLED (<=16K halfwords — P(miss) ~ 0).
// flag=1 -> read as f32, 0 -> bf16.
__global__ void k_dtype(const unsigned short* __restrict__ p, int nhalf, int* __restrict__ flag) {
    const int n = nhalf < 16384 ? nhalf : 16384;
    __shared__ unsigned int sAny[256], sOr[256];
    unsigned int any = 0, orEven = 0;
    for (int i = threadIdx.x; i < n; i += 256) {
        const unsigned short u = p[i];
        const float a = fabsf(bf2f(u));
        if (!(a <= 1e6f)) any = 1u;
        if ((i & 1) == 0) orEven |= u;
    }
    sAny[threadIdx.x] = any; sOr[threadIdx.x] = orEven;
    __syncthreads();
    for (int s = 128; s > 0; s >>= 1) {
        if (threadIdx.x < s) {
            sAny[threadIdx.x] |= sAny[threadIdx.x + s];
            sOr[threadIdx.x]  |= sOr[threadIdx.x + s];
        }
        __syncthreads();
    }
    if (threadIdx.x == 0) *flag = (sAny[0] || sOr[0] == 0u) ? 1 : 0;
}

// int64 detector, SAMPLED: if all sampled odd 32-bit words are zero -> int64
__global__ void k_i64(const unsigned int* __restrict__ p, long long nwords, int* __restrict__ flag) {
    const long long lim = nwords < 16384 ? nwords : 16384;
    __shared__ unsigned int s[256];
    unsigned int acc = 0;
    for (long long w = 1 + 2 * (long long)threadIdx.x; w < lim; w += 512) acc |= p[w];
    s[threadIdx.x] = acc;
    __syncthreads();
    for (int st = 128; st > 0; st >>= 1) {
        if (threadIdx.x < st) s[threadIdx.x] |= s[threadIdx.x + st];
        __syncthreads();
    }
    if (threadIdx.x == 0) *flag = (s[0] == 0u) ? 1 : 0;
}

__global__ void k_cvt_f32(const void* __restrict__ src, float* __restrict__ dst,
                          int n, const int* __restrict__ flag) {
    int i = blockIdx.x * 256 + threadIdx.x;
    if (i >= n) return;
    dst[i] = (*flag) ? ((const float*)src)[i] : bf2f(((const unsigned short*)src)[i]);
}

__global__ void k_cvt_bf16(const void* __restrict__ src, __hip_bfloat16* __restrict__ dst,
                           int n, const int* __restrict__ flag) {
    int i = blockIdx.x * 256 + threadIdx.x;
    if (i >= n) return;
    if (*flag) dst[i] = __float2bfloat16(((const float*)src)[i]);
    else ((unsigned short*)dst)[i] = ((const unsigned short*)src)[i];
}

__global__ void k_counts(const void* __restrict__ eidx, const int* __restrict__ fi64,
                         float* __restrict__ counts, int E_) {
    int e = blockIdx.x * 256 + threadIdx.x;
    if (e < E_) atomicAdd(&counts[geti(eidx, (long long)E_ + e, *fi64)], 1.0f);
}

__global__ void k_rowptr(const void* __restrict__ gi, const int* __restrict__ fi64,
                         int* __restrict__ rowptr, int N_, int B_) {
    int g = blockIdx.x * 256 + threadIdx.x;
    if (g > B_) return;
    const int f64 = *fi64;
    int lo = 0, hi = N_;
    while (lo < hi) { int mid = (lo + hi) >> 1; if (geti(gi, mid, f64) < g) lo = mid + 1; else hi = mid; }
    rowptr[g] = lo;
}

// lin0: out = relu(nf @ lin0_w + b)
__global__ __launch_bounds__(256) void k_lin0(const void* __restrict__ nf_raw,
                                              const float* __restrict__ w,
                                              const float* __restrict__ b,
                                              float* __restrict__ out,
                                              const int* __restrict__ flag) {
    const int ln = threadIdx.x >> 6;
    const int d = threadIdx.x & 63;
    const int n = blockIdx.x * 4 + ln;
    const int isf32 = *flag;
    __shared__ float s_nf[4][76];
    const size_t base = (size_t)n * 75;
    s_nf[ln][d] = isf32 ? ((const float*)nf_raw)[base + d] : bf2f(((const unsigned short*)nf_raw)[base + d]);
    if (d < 11) s_nf[ln][64 + d] = isf32 ? ((const float*)nf_raw)[base + 64 + d]
                                         : bf2f(((const unsigned short*)nf_raw)[base + 64 + d]);
    __syncthreads();
    float acc = b[d];
    #pragma unroll
    for (int i = 0; i < 75; ++i) acc += s_nf[ln][i] * w[i * 64 + d];
    out[(size_t)n * 64 + d] = fmaxf(acc, 0.0f);
}

// h1 = relu(ef @ w1 + b1) -> bf16
__global__ __launch_bounds__(256) void k1_h1(const void* __restrict__ ef_raw,
                                             const float* __restrict__ w1,
                                             const float* __restrict__ b1,
                                             __hip_bfloat16* __restrict__ h1,
                                             const int* __restrict__ flag) {
    const int le = threadIdx.x >> 7;
    const int j = threadIdx.x & 127;
    const int e = blockIdx.x * 2 + le;
    const int isf32 = *flag;
    __shared__ float efs[2][16];
    if (j < 16) {
        const size_t idx = (size_t)e * 16 + j;
        efs[le][j] = isf32 ? ((const float*)ef_raw)[idx] : bf2f(((const unsigned short*)ef_raw)[idx]);
    }
    __syncthreads();
    float acc = b1[j];
    #pragma unroll
    for (int i = 0; i < 16; ++i) acc += efs[le][i] * w1[i * 128 + j];
    h1[(size_t)e * 128 + j] = __float2bfloat16(fmaxf(acc, 0.0f));
}

// W = h1 @ w2 + b2 : MFMA 16x16x32 bf16, 128x128 tile (device-check-verified)
__global__ __launch_bounds__(256) void k2_wgemm(const __hip_bfloat16* __restrict__ h1,
                                                const __hip_bfloat16* __restrict__ w2,
                                                const float* __restrict__ b2,
                                                __hip_bfloat16* __restrict__ W, int e_base) {
    __shared__ __hip_bfloat16 As[128][72];
    __shared__ __hip_bfloat16 Bs[128][72];
    const int tid = threadIdx.x;
    const int le0 = blockIdx.x * 128;
    const int ge0 = e_base + le0;
    const int n0 = blockIdx.y * 128;
    const int wave = tid >> 6, lane = tid & 63;
    const int wm = (wave >> 1) * 64, wn = (wave & 1) * 64;
    const int lr = lane & 15, quad = lane >> 4;
    floatx4 acc[4][4] = {};
    for (int kst = 0; kst < 2; ++kst) {
        const int kb = kst * 64;
        #pragma unroll
        for (int i = 0; i < 4; ++i) {
            int chunk = i * 256 + tid;
            int r = chunk >> 3, c = (chunk & 7) * 8;
            *(int4*)(&As[r][c]) = *(const int4*)(h1 + (size_t)(ge0 + r) * 128 + kb + c);
        }
        #pragma unroll
        for (int i = 0; i < 4; ++i) {
            int chunk = i * 256 + tid;
            int k = chunk >> 4, c = (chunk & 15) * 8;
            int4 v = *(const int4*)(w2 + (size_t)(kb + k) * 4096 + n0 + c);
            const __hip_bfloat16* pv = (const __hip_bfloat16*)&v;
            #pragma unroll
            for (int jj = 0; jj < 8; ++jj) Bs[c + jj][k] = pv[jj];
        }
        __syncthreads();
        #pragma unroll
        for (int ks = 0; ks < 64; ks += 32) {
            short8 af[4], bfr[4];
            #pragma unroll
            for (int mt = 0; mt < 4; ++mt)
                af[mt] = *(const short8*)(&As[wm + mt * 16 + lr][ks + quad * 8]);
            #pragma unroll
            for (int nt = 0; nt < 4; ++nt)
                bfr[nt] = *(const short8*)(&Bs[wn + nt * 16 + lr][ks + quad * 8]);
            #pragma unroll
            for (int mt = 0; mt < 4; ++mt)
                #pragma unroll
                for (int nt = 0; nt < 4; ++nt)
                    acc[mt][nt] = __builtin_amdgcn_mfma_f32_16x16x32_bf16(af[mt], bfr[nt], acc[mt][nt], 0, 0, 0);
        }
        __syncthreads();
    }
    #pragma unroll
    for (int mt = 0; mt < 4; ++mt)
        #pragma unroll
        for (int nt = 0; nt < 4; ++nt) {
            const int col = n0 + wn + nt * 16 + lr;
            const float bias = b2[col];
            #pragma unroll
            for (int r = 0; r < 4; ++r) {
                const int row = le0 + wm + mt * 16 + quad * 4 + r;
                W[(size_t)row * 4096 + col] = __float2bfloat16(acc[mt][nt][r] + bias);
            }
        }
}

// self-check on 8 rows with varied residues mod 128
__global__ void k_check(const unsigned short* __restrict__ Wb,
                        const __hip_bfloat16* __restrict__ h1,
                        const float* __restrict__ w2f, const float* __restrict__ b2,
                        int e_base, int EC, int* __restrict__ flag2) {
    const int i = blockIdx.x * 256 + threadIdx.x;
    const int se = i >> 12, n = i & 4095;
    const int blk = EC >> 3;
    const int le = se * blk + ((se * 1777 + 123) & (blk - 1));
    const size_t ge = (size_t)(e_base + le);
    float ref = b2[n];
    for (int k = 0; k < 128; ++k)
        ref += __bfloat162float(h1[ge * 128 + k]) * w2f[(size_t)k * 4096 + n];
    const float got = bf2f(Wb[(size_t)le * 4096 + n]);
    if (fabsf(got - ref) > 0.03f) *flag2 = 1;
}

__global__ __launch_bounds__(256) void k_repair(__hip_bfloat16* __restrict__ Wb,
                                                const __hip_bfloat16* __restrict__ h1,
                                                const float* __restrict__ w2f,
                                                const float* __restrict__ b2,
                                                int e_base, const int* __restrict__ flag2) {
    if (*flag2 == 0) return;
    __shared__ float As[64][128];
    const int tid = threadIdx.x;
    const int et = blockIdx.x;
    const int c = blockIdx.y * 256 + tid;
    #pragma unroll
    for (int i = 0; i < 32; ++i) {
        int idx = tid * 32 + i;
        int r = idx >> 7, k = idx & 127;
        As[r][k] = __bfloat162float(h1[(size_t)(e_base + et * 64 + r) * 128 + k]);
    }
    __syncthreads();
    float acc[64];
    const float bias = b2[c];
    #pragma unroll
    for (int r = 0; r < 64; ++r) acc[r] = bias;
    for (int k = 0; k < 128; k += 4) {
        const float b0 = w2f[(size_t)(k + 0) * 4096 + c];
        const float b1 = w2f[(size_t)(k + 1) * 4096 + c];
        const float b2v = w2f[(size_t)(k + 2) * 4096 + c];
        const float b3 = w2f[(size_t)(k + 3) * 4096 + c];
        #pragma unroll
        for (int r = 0; r < 64; ++r) {
            float4 a = *(const float4*)&As[r][k];
            acc[r] = fmaf(a.x, b0, fmaf(a.y, b1, fmaf(a.z, b2v, fmaf(a.w, b3, acc[r]))));
        }
    }
    #pragma unroll
    for (int r = 0; r < 64; ++r)
        Wb[(size_t)(et * 64 + r) * 4096 + c] = __float2bfloat16(acc[r]);
}

// msg[e] = out[src[e]] @ W[e], scatter-add to agg[dst]; one wave per edge.
// Coalesced 16B/lane W loads, shfl broadcast of out[src], xor-shfl reduce.
// (Verified equivalent to scalar k3_dumb: bit-identical output, rounds 3/4.)
__global__ __launch_bounds__(256) void k3_msg(const __hip_bfloat16* __restrict__ W,
                                              const float* __restrict__ out,
                                              const void* __restrict__ eidx,
                                              const int* __restrict__ fi64,
                                              float* __restrict__ agg,
                                              int e_limit, int e_base) {
    const int wid = (int)((blockIdx.x * 256 + threadIdx.x) >> 6);
    const int e = e_base + wid;
    if (e >= e_limit) return;  // wave-uniform
    const int lane = threadIdx.x & 63;
    const int f64 = *fi64;
    const int s = geti(eidx, e, f64);
    const int d = geti(eidx, (long long)GE + e, f64);
    const float ov = out[(size_t)s * 64 + lane];
    float p[8] = {0.f, 0.f, 0.f, 0.f, 0.f, 0.f, 0.f, 0.f};
    const __hip_bfloat16* We = W + (size_t)(e - e_base) * 4096;
    #pragma unroll
    for (int st = 0; st < 8; ++st) {
        int4 v = *(const int4*)(We + st * 512 + lane * 8);  // row = st*8+lane/8, cols (lane&7)*8..+8
        const __hip_bfloat16* pv = (const __hip_bfloat16*)&v;
        const float x = __shfl(ov, st * 8 + (lane >> 3));
        #pragma unroll
        for (int j = 0; j < 8; ++j) p[j] += x * __bfloat162float(pv[j]);
    }
    #pragma unroll
    for (int off = 8; off <= 32; off <<= 1) {
        #pragma unroll
        for (int j = 0; j < 8; ++j) p[j] += __shfl_xor(p[j], off);
    }
    if (lane < 8) {
        float* ap = agg + (size_t)d * 64 + lane * 8;
        #pragma unroll
        for (int j = 0; j < 8; ++j) atomicAdd(ap + j, p[j]);
    }
}

__global__ __launch_bounds__(256) void k4_gru(const float* __restrict__ agg,
                                              const float* __restrict__ counts,
                                              const float* __restrict__ cbias,
                                              const float* __restrict__ w_ih,
                                              const float* __restrict__ w_hh,
                                              const float* __restrict__ b_ih,
                                              const float* __restrict__ b_hh,
                                              float* __restrict__ out) {
    const int ln = threadIdx.x >> 6;
    const int d = threadIdx.x & 63;
    const int n = blockIdx.x * 4 + ln;
    __shared__ float sm[4][64], sh[4][64];
    const float cnt = fmaxf(counts[n], 1.0f);
    const float m = fmaxf(agg[(size_t)n * 64 + d] / cnt + cbias[d], 0.0f);
    const float h = out[(size_t)n * 64 + d];
    sm[ln][d] = m; sh[ln][d] = h;
    __syncthreads();
    float aih[3], ahh[3];
    #pragma unroll
    for (int g = 0; g < 3; ++g) { aih[g] = b_ih[g * 64 + d]; ahh[g] = b_hh[g * 64 + d]; }
    for (int k4 = 0; k4 < 64; k4 += 4) {
        float4 vih[3], vhh[3];
        #pragma unroll
        for (int g = 0; g < 3; ++g) {
            vih[g] = *(const float4*)(w_ih + (size_t)(g * 64 + d) * 64 + k4);
            vhh[g] = *(const float4*)(w_hh + (size_t)(g * 64 + d) * 64 + k4);
        }
        #pragma unroll
        for (int j = 0; j < 4; ++j) {
            const float mk = sm[ln][k4 + j];
            const float hk = sh[ln][k4 + j];
            #pragma unroll
            for (int g = 0; g < 3; ++g) {
                aih[g] += mk * ((const float*)&vih[g])[j];
                ahh[g] += hk * ((const float*)&vhh[g])[j];
            }
        }
    }
    const float r = sigm(aih[0] + ahh[0]);
    const float z = sigm(aih[1] + ahh[1]);
    const float nn = tanhf(aih[2] + r * ahh[2]);
    out[(size_t)n * 64 + d] = (1.0f - z) * nn + z * h;
}

__global__ __launch_bounds__(256) void k5_lstm(float* __restrict__ qstar,
                                               float* __restrict__ hs, float* __restrict__ cs,
                                               const float* __restrict__ w_ih,
                                               const float* __restrict__ w_hh,
                                               const float* __restrict__ b_ih,
                                               const float* __restrict__ b_hh) {
    const int g = blockIdx.x;
    const int j = threadIdx.x;
    __shared__ float qs[128], hv[64], gates[256];
    if (j < 128) qs[j] = qstar[(size_t)g * 128 + j];
    else if (j < 192) hv[j - 128] = hs[(size_t)g * 64 + (j - 128)];
    __syncthreads();
    float acc = b_ih[j] + b_hh[j];
    for (int k4 = 0; k4 < 128; k4 += 4) {
        float4 v = *(const float4*)(w_ih + (size_t)j * 128 + k4);
        const float* pv = (const float*)&v;
        #pragma unroll
        for (int t = 0; t < 4; ++t) acc += qs[k4 + t] * pv[t];
    }
    for (int k4 = 0; k4 < 64; k4 += 4) {
        float4 v = *(const float4*)(w_hh + (size_t)j * 64 + k4);
        const float* pv = (const float*)&v;
        #pragma unroll
        for (int t = 0; t < 4; ++t) acc += hv[k4 + t] * pv[t];
    }
    gates[j] = acc;
    __syncthreads();
    if (j < 64) {
        const float ig = sigm(gates[j]);
        const float fg = sigm(gates[64 + j]);
        const float gg = tanhf(gates[128 + j]);
        const float og = sigm(gates[192 + j]);
        const float c = fg * cs[(size_t)g * 64 + j] + ig * gg;
        const float h = og * tanhf(c);
        cs[(size_t)g * 64 + j] = c;
        hs[(size_t)g * 64 + j] = h;
        qstar[(size_t)g * 128 + j] = h;
    }
}

// Set2Set attention: single-pass online softmax, wave per graph
// (verified equivalent to LDS 3-pass version: identical output, rounds 3/4)
__global__ __launch_bounds__(64) void k5_attn(const float* __restrict__ out,
                                              const float* __restrict__ hs,
                                              const int* __restrict__ rowptr,
                                              float* __restrict__ qstar) {
    const int g = blockIdx.x;
    const int lane = threadIdx.x;
    const float q = hs[(size_t)g * 64 + lane];
    const int start = rowptr[g], end = rowptr[g + 1];
    float m = -3.4e38f, S = 0.0f, racc = 0.0f;
    for (int n = start; n < end; ++n) {
        const float ov = out[(size_t)n * 64 + lane];
        float p = ov * q;
        #pragma unroll
        for (int off = 1; off < 64; off <<= 1) p += __shfl_xor(p, off);
        if (p > m) {
            const float sc = __expf(m - p);
            S = S * sc + 1.0f;
            racc = racc * sc + ov;
            m = p;
        } else {
            const float w = __expf(p - m);
            S += w;
            racc += w * ov;
        }
    }
    qstar[(size_t)g * 128 + 64 + lane] = racc / (S + 1e-16f);
}

// final: pack q_star then feat_map into FLOAT32 d_out
__global__ void k_out(const float* __restrict__ qstar, const float* __restrict__ outb,
                      float* __restrict__ dst, int nq, int nfeat, int out_n) {
    int i = blockIdx.x * 256 + threadIdx.x;
    if (i >= out_n) return;
    float v = 0.0f;
    if (i < nq) v = qstar[i];
    else if (i - nq < nfeat) v = outb[i - nq];
    dst[i] = v;
}

extern "C" void kernel_launch(void* const* d_in, const int* in_sizes, int n_in,
                              void* d_out, int out_size, void* d_ws, size_t ws_size,
                              hipStream_t stream) {
    constexpr int N = GN, E = GE, B = GB;

    char* ws = (char*)d_ws;
    size_t off = 0;
    auto alloc = [&](size_t bytes) { size_t o = off; off = (off + bytes + 255) & ~(size_t)255; return o; };

    int*   fl     = (int*)  (ws + alloc(19 * 4));
    int*   flagE  = (int*)  (ws + alloc(256));
    int*   flagG  = (int*)  (ws + alloc(256));
    int*   flag2  = (int*)  (ws + alloc(256));
    float* counts = (float*)(ws + alloc((size_t)N * 4));
    int*   rowptr = (int*)  (ws + alloc((size_t)(B + 1) * 4));
    float* outbuf = (float*)(ws + alloc((size_t)N * 64 * 4));
    float* agg    = (float*)(ws + alloc((size_t)N * 64 * 4));
    float* qstar  = (float*)(ws + alloc((size_t)B * 128 * 4));
    float* hsb    = (float*)(ws + alloc((size_t)B * 64 * 4));
    float* csb    = (float*)(ws + alloc((size_t)B * 64 * 4));
    __hip_bfloat16* h1   = (__hip_bfloat16*)(ws + alloc((size_t)E * 128 * 2));
    __hip_bfloat16* w2bf = (__hip_bfloat16*)(ws + alloc((size_t)128 * 4096 * 2));

    const int fidx[15]  = {4, 5, 6, 7, 8, 9, 10, 11, 12, 13, 14, 15, 16, 17, 18};
    const int fsize[15] = {75 * 64, 64, 16 * 128, 128, 128 * 4096, 4096, 64,
                           192 * 64, 192 * 64, 192, 192, 256 * 128, 256 * 64, 256, 256};
    float* F[19] = {};
    for (int t = 0; t < 15; ++t) F[fidx[t]] = (float*)(ws + alloc((size_t)fsize[t] * 4));

    const size_t off_W = off;
    __hip_bfloat16* Wbuf = (__hip_bfloat16*)(ws + off_W);
    int EC = E;
    while (EC > 256 && off_W + (size_t)EC * 4096 * 2 > ws_size) EC >>= 1;
    const bool full = (EC == E);

    // sampled dtype detection (~10 us total)
    k_dtype<<<1, 256, 0, stream>>>((const unsigned short*)d_in[0], N * 75, fl + 0);
    k_dtype<<<1, 256, 0, stream>>>((const unsigned short*)d_in[1], E * 16, fl + 1);
    for (int t = 0; t < 15; ++t)
        k_dtype<<<1, 256, 0, stream>>>((const unsigned short*)d_in[fidx[t]], fsize[t], fl + fidx[t]);
    k_i64<<<1, 256, 0, stream>>>((const unsigned int*)d_in[2], (long long)2 * E, flagE);
    k_i64<<<1, 256, 0, stream>>>((const unsigned int*)d_in[3], (long long)N, flagG);
    hipMemsetAsync(flag2, 0, 4, stream);

    for (int t = 0; t < 15; ++t) {
        int n = fsize[t];
        k_cvt_f32<<<(n + 255) / 256, 256, 0, stream>>>(d_in[fidx[t]], F[fidx[t]], n, fl + fidx[t]);
    }
    k_cvt_bf16<<<(128 * 4096 + 255) / 256, 256, 0, stream>>>(d_in[8], w2bf, 128 * 4096, fl + 8);

    hipMemsetAsync(counts, 0, (size_t)N * 4, stream);
    hipMemsetAsync(qstar, 0, (size_t)B * 128 * 4, stream);
    hipMemsetAsync(hsb, 0, (size_t)B * 64 * 4, stream);
    hipMemsetAsync(csb, 0, (size_t)B * 64 * 4, stream);

    k_counts<<<E / 256, 256, 0, stream>>>(d_in[2], flagE, counts, E);
    k_rowptr<<<(B + 1 + 255) / 256, 256, 0, stream>>>(d_in[3], flagG, rowptr, N, B);
    k_lin0<<<N / 4, 256, 0, stream>>>(d_in[0], F[4], F[5], outbuf, fl + 0);
    k1_h1<<<E / 2, 256, 0, stream>>>(d_in[1], F[6], F[7], h1, fl + 1);

    auto gen_W = [&](int c, int ec) {
        dim3 g2(ec / 128, 32);
        k2_wgemm<<<g2, 256, 0, stream>>>(h1, w2bf, F[9], Wbuf, c);
        k_check<<<8 * 4096 / 256, 256, 0, stream>>>((const unsigned short*)Wbuf, h1,
                                                    F[8], F[9], c, ec, flag2);
        dim3 gr(ec / 64, 16);
        k_repair<<<gr, 256, 0, stream>>>(Wbuf, h1, F[8], F[9], c, flag2);
    };

    if (full) gen_W(0, E);
    for (int it = 0; it < 3; ++it) {
        hipMemsetAsync(agg, 0, (size_t)N * 64 * 4, stream);
        if (full) {
            k3_msg<<<E / 4, 256, 0, stream>>>(Wbuf, outbuf, d_in[2], flagE, agg, E, 0);
        } else {
            for (int c = 0; c < E; c += EC) {
                gen_W(c, EC);
                k3_msg<<<EC / 4, 256, 0, stream>>>(Wbuf, outbuf, d_in[2], flagE, agg, c + EC, c);
            }
        }
        k4_gru<<<N / 4, 256, 0, stream>>>(agg, counts, F[10], F[11], F[12], F[13], F[14], outbuf);
    }
    for (int t = 0; t < 3; ++t) {
        k5_lstm<<<B, 256, 0, stream>>>(qstar, hsb, csb, F[15], F[16], F[17], F[18]);
        k5_attn<<<B, 64, 0, stream>>>(outbuf, hsb, rowptr, qstar);
    }
    k_out<<<(out_size + 255) / 256, 256, 0, stream>>>(qstar, outbuf, (float*)d_out,
                                                      B * 128, N * 64, out_size);
}

// Round 7
// 4273.128 us; speedup vs baseline: 2.9467x; 1.4373x over previous
//
#include <hip/hip_runtime.h>
#include <hip/hip_bf16.h>

#define GN 65536
#define GE 131072
#define GB 2048

typedef __attribute__((ext_vector_type(8))) short short8;
typedef __attribute__((ext_vector_type(4))) float floatx4;

static __device__ __forceinline__ float sigm(float x) { return 1.0f / (1.0f + __expf(-x)); }
static __device__ __forceinline__ float bf2f(unsigned short u) {
    union { unsigned int i; float f; } v; v.i = ((unsigned int)u) << 16; return v.f;
}
static __device__ __forceinline__ int geti(const void* p, long long i, int f64) {
    return f64 ? (int)((const long long*)p)[i] : ((const int*)p)[i];
}

// ---- batched per-tensor float dtype detector (one block per tensor) ----
struct DetectArgs { const void* src[17]; int nhalf[17]; int fi[17]; };
__global__ void k_dtype_all(DetectArgs a, int* __restrict__ flags) {
    const unsigned short* p = (const unsigned short*)a.src[blockIdx.x];
    const int n0 = a.nhalf[blockIdx.x];
    const int n = n0 < 16384 ? n0 : 16384;
    __shared__ unsigned int sAny[256], sOr[256];
    unsigned int any = 0, orEven = 0;
    for (int i = threadIdx.x; i < n; i += 256) {
        const unsigned short u = p[i];
        const float av = fabsf(bf2f(u));
        if (!(av <= 1e6f)) any = 1u;
        if ((i & 1) == 0) orEven |= u;
    }
    sAny[threadIdx.x] = any; sOr[threadIdx.x] = orEven;
    __syncthreads();
    for (int s = 128; s > 0; s >>= 1) {
        if (threadIdx.x < s) {
            sAny[threadIdx.x] |= sAny[threadIdx.x + s];
            sOr[threadIdx.x]  |= sOr[threadIdx.x + s];
        }
        __syncthreads();
    }
    if (threadIdx.x == 0) flags[a.fi[blockIdx.x]] = (sAny[0] || sOr[0] == 0u) ? 1 : 0;
}

// int64 detector, sampled
__global__ void k_i64(const unsigned int* __restrict__ p, long long nwords, int* __restrict__ flag) {
    const long long lim = nwords < 16384 ? nwords : 16384;
    __shared__ unsigned int s[256];
    unsigned int acc = 0;
    for (long long w = 1 + 2 * (long long)threadIdx.x; w < lim; w += 512) acc |= p[w];
    s[threadIdx.x] = acc;
    __syncthreads();
    for (int st = 128; st > 0; st >>= 1) {
        if (threadIdx.x < st) s[threadIdx.x] |= s[threadIdx.x + st];
        __syncthreads();
    }
    if (threadIdx.x == 0) *flag = (s[0] == 0u) ? 1 : 0;
}

// ---- batched f32 canonicalization of the 15 small float tensors ----
struct CvtArgs { const void* src[15]; float* dst[15]; int n[15]; int fi[15]; int pre[16]; };
__global__ void k_cvt_all(CvtArgs a, const int* __restrict__ flags) {
    const int b = blockIdx.x;
    int t = 0;
    while (t < 14 && b >= a.pre[t + 1]) ++t;
    const int i = (b - a.pre[t]) * 256 + threadIdx.x;
    if (i >= a.n[t]) return;
    const int f = flags[a.fi[t]];
    a.dst[t][i] = f ? ((const float*)a.src[t])[i] : bf2f(((const unsigned short*)a.src[t])[i]);
}

__global__ void k_cvt_bf16(const void* __restrict__ src, __hip_bfloat16* __restrict__ dst,
                           int n, const int* __restrict__ flag) {
    int i = blockIdx.x * 256 + threadIdx.x;
    if (i >= n) return;
    if (*flag) dst[i] = __float2bfloat16(((const float*)src)[i]);
    else ((unsigned short*)dst)[i] = ((const unsigned short*)src)[i];
}

__global__ void k_counts(const void* __restrict__ eidx, const int* __restrict__ fi64,
                         float* __restrict__ counts, int E_) {
    int e = blockIdx.x * 256 + threadIdx.x;
    if (e < E_) atomicAdd(&counts[geti(eidx, (long long)E_ + e, *fi64)], 1.0f);
}

__global__ void k_rowptr(const void* __restrict__ gi, const int* __restrict__ fi64,
                         int* __restrict__ rowptr, int N_, int B_) {
    int g = blockIdx.x * 256 + threadIdx.x;
    if (g > B_) return;
    const int f64 = *fi64;
    int lo = 0, hi = N_;
    while (lo < hi) { int mid = (lo + hi) >> 1; if (geti(gi, mid, f64) < g) lo = mid + 1; else hi = mid; }
    rowptr[g] = lo;
}

// lin0: out = relu(nf @ lin0_w + b)
__global__ __launch_bounds__(256) void k_lin0(const void* __restrict__ nf_raw,
                                              const float* __restrict__ w,
                                              const float* __restrict__ b,
                                              float* __restrict__ out,
                                              const int* __restrict__ flag) {
    const int ln = threadIdx.x >> 6;
    const int d = threadIdx.x & 63;
    const int n = blockIdx.x * 4 + ln;
    const int isf32 = *flag;
    __shared__ float s_nf[4][76];
    const size_t base = (size_t)n * 75;
    s_nf[ln][d] = isf32 ? ((const float*)nf_raw)[base + d] : bf2f(((const unsigned short*)nf_raw)[base + d]);
    if (d < 11) s_nf[ln][64 + d] = isf32 ? ((const float*)nf_raw)[base + 64 + d]
                                         : bf2f(((const unsigned short*)nf_raw)[base + 64 + d]);
    __syncthreads();
    float acc = b[d];
    #pragma unroll
    for (int i = 0; i < 75; ++i) acc += s_nf[ln][i] * w[i * 64 + d];
    out[(size_t)n * 64 + d] = fmaxf(acc, 0.0f);
}

// h1 = relu(ef @ w1 + b1) -> bf16
__global__ __launch_bounds__(256) void k1_h1(const void* __restrict__ ef_raw,
                                             const float* __restrict__ w1,
                                             const float* __restrict__ b1,
                                             __hip_bfloat16* __restrict__ h1,
                                             const int* __restrict__ flag) {
    const int le = threadIdx.x >> 7;
    const int j = threadIdx.x & 127;
    const int e = blockIdx.x * 2 + le;
    const int isf32 = *flag;
    __shared__ float efs[2][16];
    if (j < 16) {
        const size_t idx = (size_t)e * 16 + j;
        efs[le][j] = isf32 ? ((const float*)ef_raw)[idx] : bf2f(((const unsigned short*)ef_raw)[idx]);
    }
    __syncthreads();
    float acc = b1[j];
    #pragma unroll
    for (int i = 0; i < 16; ++i) acc += efs[le][i] * w1[i * 128 + j];
    h1[(size_t)e * 128 + j] = __float2bfloat16(fmaxf(acc, 0.0f));
}

// W = h1 @ w2 + b2 : MFMA 16x16x32 bf16, 128x128 tile (device-check-verified)
__global__ __launch_bounds__(256) void k2_wgemm(const __hip_bfloat16* __restrict__ h1,
                                                const __hip_bfloat16* __restrict__ w2,
                                                const float* __restrict__ b2,
                                                __hip_bfloat16* __restrict__ W, int e_base) {
    __shared__ __hip_bfloat16 As[128][72];
    __shared__ __hip_bfloat16 Bs[128][72];
    const int tid = threadIdx.x;
    const int le0 = blockIdx.x * 128;
    const int ge0 = e_base + le0;
    const int n0 = blockIdx.y * 128;
    const int wave = tid >> 6, lane = tid & 63;
    const int wm = (wave >> 1) * 64, wn = (wave & 1) * 64;
    const int lr = lane & 15, quad = lane >> 4;
    floatx4 acc[4][4] = {};
    for (int kst = 0; kst < 2; ++kst) {
        const int kb = kst * 64;
        #pragma unroll
        for (int i = 0; i < 4; ++i) {
            int chunk = i * 256 + tid;
            int r = chunk >> 3, c = (chunk & 7) * 8;
            *(int4*)(&As[r][c]) = *(const int4*)(h1 + (size_t)(ge0 + r) * 128 + kb + c);
        }
        #pragma unroll
        for (int i = 0; i < 4; ++i) {
            int chunk = i * 256 + tid;
            int k = chunk >> 4, c = (chunk & 15) * 8;
            int4 v = *(const int4*)(w2 + (size_t)(kb + k) * 4096 + n0 + c);
            const __hip_bfloat16* pv = (const __hip_bfloat16*)&v;
            #pragma unroll
            for (int jj = 0; jj < 8; ++jj) Bs[c + jj][k] = pv[jj];
        }
        __syncthreads();
        #pragma unroll
        for (int ks = 0; ks < 64; ks += 32) {
            short8 af[4], bfr[4];
            #pragma unroll
            for (int mt = 0; mt < 4; ++mt)
                af[mt] = *(const short8*)(&As[wm + mt * 16 + lr][ks + quad * 8]);
            #pragma unroll
            for (int nt = 0; nt < 4; ++nt)
                bfr[nt] = *(const short8*)(&Bs[wn + nt * 16 + lr][ks + quad * 8]);
            #pragma unroll
            for (int mt = 0; mt < 4; ++mt)
                #pragma unroll
                for (int nt = 0; nt < 4; ++nt)
                    acc[mt][nt] = __builtin_amdgcn_mfma_f32_16x16x32_bf16(af[mt], bfr[nt], acc[mt][nt], 0, 0, 0);
        }
        __syncthreads();
    }
    #pragma unroll
    for (int mt = 0; mt < 4; ++mt)
        #pragma unroll
        for (int nt = 0; nt < 4; ++nt) {
            const int col = n0 + wn + nt * 16 + lr;
            const float bias = b2[col];
            #pragma unroll
            for (int r = 0; r < 4; ++r) {
                const int row = le0 + wm + mt * 16 + quad * 4 + r;
                W[(size_t)row * 4096 + col] = __float2bfloat16(acc[mt][nt][r] + bias);
            }
        }
}

// self-check on 8 rows with varied residues mod 128
__global__ void k_check(const unsigned short* __restrict__ Wb,
                        const __hip_bfloat16* __restrict__ h1,
                        const float* __restrict__ w2f, const float* __restrict__ b2,
                        int e_base, int EC, int* __restrict__ flag2) {
    const int i = blockIdx.x * 256 + threadIdx.x;
    const int se = i >> 12, n = i & 4095;
    const int blk = EC >> 3;
    const int le = se * blk + ((se * 1777 + 123) & (blk - 1));
    const size_t ge = (size_t)(e_base + le);
    float ref = b2[n];
    for (int k = 0; k < 128; ++k)
        ref += __bfloat162float(h1[ge * 128 + k]) * w2f[(size_t)k * 4096 + n];
    const float got = bf2f(Wb[(size_t)le * 4096 + n]);
    if (fabsf(got - ref) > 0.03f) *flag2 = 1;
}

__global__ __launch_bounds__(256) void k_repair(__hip_bfloat16* __restrict__ Wb,
                                                const __hip_bfloat16* __restrict__ h1,
                                                const float* __restrict__ w2f,
                                                const float* __restrict__ b2,
                                                int e_base, const int* __restrict__ flag2) {
    if (*flag2 == 0) return;
    __shared__ float As[64][128];
    const int tid = threadIdx.x;
    const int et = blockIdx.x;
    const int c = blockIdx.y * 256 + tid;
    #pragma unroll
    for (int i = 0; i < 32; ++i) {
        int idx = tid * 32 + i;
        int r = idx >> 7, k = idx & 127;
        As[r][k] = __bfloat162float(h1[(size_t)(e_base + et * 64 + r) * 128 + k]);
    }
    __syncthreads();
    float acc[64];
    const float bias = b2[c];
    #pragma unroll
    for (int r = 0; r < 64; ++r) acc[r] = bias;
    for (int k = 0; k < 128; k += 4) {
        const float b0 = w2f[(size_t)(k + 0) * 4096 + c];
        const float b1 = w2f[(size_t)(k + 1) * 4096 + c];
        const float b2v = w2f[(size_t)(k + 2) * 4096 + c];
        const float b3 = w2f[(size_t)(k + 3) * 4096 + c];
        #pragma unroll
        for (int r = 0; r < 64; ++r) {
            float4 a = *(const float4*)&As[r][k];
            acc[r] = fmaf(a.x, b0, fmaf(a.y, b1, fmaf(a.z, b2v, fmaf(a.w, b3, acc[r]))));
        }
    }
    #pragma unroll
    for (int r = 0; r < 64; ++r)
        Wb[(size_t)(et * 64 + r) * 4096 + c] = __float2bfloat16(acc[r]);
}

// msg[e] = out[src[e]] @ W[e], scatter-add to agg[dst]; one wave per edge
__global__ __launch_bounds__(256) void k3_msg(const __hip_bfloat16* __restrict__ W,
                                              const float* __restrict__ out,
                                              const void* __restrict__ eidx,
                                              const int* __restrict__ fi64,
                                              float* __restrict__ agg,
                                              int e_limit, int e_base) {
    const int wid = (int)((blockIdx.x * 256 + threadIdx.x) >> 6);
    const int e = e_base + wid;
    if (e >= e_limit) return;
    const int lane = threadIdx.x & 63;
    const int f64 = *fi64;
    const int s = geti(eidx, e, f64);
    const int d = geti(eidx, (long long)GE + e, f64);
    const float ov = out[(size_t)s * 64 + lane];
    float p[8] = {0.f, 0.f, 0.f, 0.f, 0.f, 0.f, 0.f, 0.f};
    const __hip_bfloat16* We = W + (size_t)(e - e_base) * 4096;
    #pragma unroll
    for (int st = 0; st < 8; ++st) {
        int4 v = *(const int4*)(We + st * 512 + lane * 8);
        const __hip_bfloat16* pv = (const __hip_bfloat16*)&v;
        const float x = __shfl(ov, st * 8 + (lane >> 3));
        #pragma unroll
        for (int j = 0; j < 8; ++j) p[j] += x * __bfloat162float(pv[j]);
    }
    #pragma unroll
    for (int off = 8; off <= 32; off <<= 1) {
        #pragma unroll
        for (int j = 0; j < 8; ++j) p[j] += __shfl_xor(p[j], off);
    }
    if (lane < 8) {
        float* ap = agg + (size_t)d * 64 + lane * 8;
        #pragma unroll
        for (int j = 0; j < 8; ++j) atomicAdd(ap + j, p[j]);
    }
}

// GRU v2: wave = 64 nodes (lane=node); activations register-resident via
// conflict-free LDS transpose (stride 65); d-loop is wave-uniform so all
// weight/bias reads are scalar (SMEM) loads. Arithmetic floor ~20 us.
__global__ __launch_bounds__(256) void k4_gru(const float* __restrict__ agg,
                                              const float* __restrict__ counts,
                                              const float* __restrict__ cbias,
                                              const float* __restrict__ w_ih,
                                              const float* __restrict__ w_hh,
                                              const float* __restrict__ b_ih,
                                              const float* __restrict__ b_hh,
                                              float* __restrict__ out) {
    const int wv = threadIdx.x >> 6;
    const int lane = threadIdx.x & 63;
    const int nb0 = blockIdx.x * 256 + wv * 64;
    __shared__ float slab_all[4][64][65];
    float (*slab)[65] = slab_all[wv];

    // stage agg (coalesced) -> LDS -> m regs (transposed, stride-65)
    for (int r = 0; r < 64; ++r)
        slab[r][lane] = agg[(size_t)(nb0 + r) * 64 + lane];
    const float rcnt = 1.0f / fmaxf(counts[nb0 + lane], 1.0f);
    __syncthreads();
    float m[64];
    #pragma unroll
    for (int k = 0; k < 64; ++k)
        m[k] = fmaxf(slab[lane][k] * rcnt + cbias[k], 0.0f);
    __syncthreads();
    // stage h (out) -> LDS (kept resident for h[d] reads) -> h regs
    for (int r = 0; r < 64; ++r)
        slab[r][lane] = out[(size_t)(nb0 + r) * 64 + lane];
    __syncthreads();
    float h[64];
    #pragma unroll
    for (int k = 0; k < 64; ++k) h[k] = slab[lane][k];

    #pragma unroll 1
    for (int d = 0; d < 64; ++d) {
        float a0 = b_ih[d], a1 = b_ih[64 + d], a2 = b_ih[128 + d];
        float g0 = b_hh[d], g1 = b_hh[64 + d], g2 = b_hh[128 + d];
        const float* wi0 = w_ih + (size_t)d * 64;
        const float* wi1 = w_ih + (size_t)(64 + d) * 64;
        const float* wi2 = w_ih + (size_t)(128 + d) * 64;
        const float* wh0 = w_hh + (size_t)d * 64;
        const float* wh1 = w_hh + (size_t)(64 + d) * 64;
        const float* wh2 = w_hh + (size_t)(128 + d) * 64;
        #pragma unroll
        for (int k = 0; k < 64; ++k) {
            a0 = fmaf(m[k], wi0[k], a0);
            a1 = fmaf(m[k], wi1[k], a1);
            a2 = fmaf(m[k], wi2[k], a2);
            g0 = fmaf(h[k], wh0[k], g0);
            g1 = fmaf(h[k], wh1[k], g1);
            g2 = fmaf(h[k], wh2[k], g2);
        }
        const float r_ = sigm(a0 + g0);
        const float z  = sigm(a1 + g1);
        const float nn = tanhf(a2 + r_ * g2);
        const float hd = slab[lane][d];                 // h[d] via LDS (no dyn reg idx)
        out[(size_t)(nb0 + lane) * 64 + d] = (1.0f - z) * nn + z * hd;
    }
}

__global__ __launch_bounds__(256) void k5_lstm(float* __restrict__ qstar,
                                               float* __restrict__ hs, float* __restrict__ cs,
                                               const float* __restrict__ w_ih,
                                               const float* __restrict__ w_hh,
                                               const float* __restrict__ b_ih,
                                               const float* __restrict__ b_hh) {
    const int g = blockIdx.x;
    const int j = threadIdx.x;
    __shared__ float qs[128], hv[64], gates[256];
    if (j < 128) qs[j] = qstar[(size_t)g * 128 + j];
    else if (j < 192) hv[j - 128] = hs[(size_t)g * 64 + (j - 128)];
    __syncthreads();
    float acc = b_ih[j] + b_hh[j];
    for (int k4 = 0; k4 < 128; k4 += 4) {
        float4 v = *(const float4*)(w_ih + (size_t)j * 128 + k4);
        const float* pv = (const float*)&v;
        #pragma unroll
        for (int t = 0; t < 4; ++t) acc += qs[k4 + t] * pv[t];
    }
    for (int k4 = 0; k4 < 64; k4 += 4) {
        float4 v = *(const float4*)(w_hh + (size_t)j * 64 + k4);
        const float* pv = (const float*)&v;
        #pragma unroll
        for (int t = 0; t < 4; ++t) acc += hv[k4 + t] * pv[t];
    }
    gates[j] = acc;
    __syncthreads();
    if (j < 64) {
        const float ig = sigm(gates[j]);
        const float fg = sigm(gates[64 + j]);
        const float gg = tanhf(gates[128 + j]);
        const float og = sigm(gates[192 + j]);
        const float c = fg * cs[(size_t)g * 64 + j] + ig * gg;
        const float h = og * tanhf(c);
        cs[(size_t)g * 64 + j] = c;
        hs[(size_t)g * 64 + j] = h;
        qstar[(size_t)g * 128 + j] = h;
    }
}

// Set2Set attention: single-pass online softmax, wave per graph
__global__ __launch_bounds__(64) void k5_attn(const float* __restrict__ out,
                                              const float* __restrict__ hs,
                                              const int* __restrict__ rowptr,
                                              float* __restrict__ qstar) {
    const int g = blockIdx.x;
    const int lane = threadIdx.x;
    const float q = hs[(size_t)g * 64 + lane];
    const int start = rowptr[g], end = rowptr[g + 1];
    float m = -3.4e38f, S = 0.0f, racc = 0.0f;
    for (int n = start; n < end; ++n) {
        const float ov = out[(size_t)n * 64 + lane];
        float p = ov * q;
        #pragma unroll
        for (int off = 1; off < 64; off <<= 1) p += __shfl_xor(p, off);
        if (p > m) {
            const float sc = __expf(m - p);
            S = S * sc + 1.0f;
            racc = racc * sc + ov;
            m = p;
        } else {
            const float w = __expf(p - m);
            S += w;
            racc += w * ov;
        }
    }
    qstar[(size_t)g * 128 + 64 + lane] = racc / (S + 1e-16f);
}

__global__ void k_out(const float* __restrict__ qstar, const float* __restrict__ outb,
                      float* __restrict__ dst, int nq, int nfeat, int out_n) {
    int i = blockIdx.x * 256 + threadIdx.x;
    if (i >= out_n) return;
    float v = 0.0f;
    if (i < nq) v = qstar[i];
    else if (i - nq < nfeat) v = outb[i - nq];
    dst[i] = v;
}

extern "C" void kernel_launch(void* const* d_in, const int* in_sizes, int n_in,
                              void* d_out, int out_size, void* d_ws, size_t ws_size,
                              hipStream_t stream) {
    constexpr int N = GN, E = GE, B = GB;

    char* ws = (char*)d_ws;
    size_t off = 0;
    auto alloc = [&](size_t bytes) { size_t o = off; off = (off + bytes + 255) & ~(size_t)255; return o; };

    int*   fl     = (int*)  (ws + alloc(19 * 4));
    int*   flagE  = (int*)  (ws + alloc(256));
    int*   flagG  = (int*)  (ws + alloc(256));
    int*   flag2  = (int*)  (ws + alloc(256));
    float* counts = (float*)(ws + alloc((size_t)N * 4));
    int*   rowptr = (int*)  (ws + alloc((size_t)(B + 1) * 4));
    float* outbuf = (float*)(ws + alloc((size_t)N * 64 * 4));
    float* agg    = (float*)(ws + alloc((size_t)N * 64 * 4));
    // qstar/hs/cs contiguous -> one memset
    float* qstar  = (float*)(ws + alloc((size_t)B * 128 * 4));
    float* hsb    = (float*)(ws + alloc((size_t)B * 64 * 4));
    float* csb    = (float*)(ws + alloc((size_t)B * 64 * 4));
    __hip_bfloat16* h1   = (__hip_bfloat16*)(ws + alloc((size_t)E * 128 * 2));
    __hip_bfloat16* w2bf = (__hip_bfloat16*)(ws + alloc((size_t)128 * 4096 * 2));

    const int fidx[15]  = {4, 5, 6, 7, 8, 9, 10, 11, 12, 13, 14, 15, 16, 17, 18};
    const int fsize[15] = {75 * 64, 64, 16 * 128, 128, 128 * 4096, 4096, 64,
                           192 * 64, 192 * 64, 192, 192, 256 * 128, 256 * 64, 256, 256};
    float* F[19] = {};
    for (int t = 0; t < 15; ++t) F[fidx[t]] = (float*)(ws + alloc((size_t)fsize[t] * 4));

    const size_t off_W = off;
    __hip_bfloat16* Wbuf = (__hip_bfloat16*)(ws + off_W);
    int EC = E;
    while (EC > 256 && off_W + (size_t)EC * 4096 * 2 > ws_size) EC >>= 1;
    const bool full = (EC == E);

    // batched dtype detection: 17 tensors in one launch
    DetectArgs da;
    da.src[0] = d_in[0]; da.nhalf[0] = N * 75; da.fi[0] = 0;
    da.src[1] = d_in[1]; da.nhalf[1] = E * 16; da.fi[1] = 1;
    for (int t = 0; t < 15; ++t) { da.src[2 + t] = d_in[fidx[t]]; da.nhalf[2 + t] = fsize[t]; da.fi[2 + t] = fidx[t]; }
    k_dtype_all<<<17, 256, 0, stream>>>(da, fl);
    k_i64<<<1, 256, 0, stream>>>((const unsigned int*)d_in[2], (long long)2 * E, flagE);
    k_i64<<<1, 256, 0, stream>>>((const unsigned int*)d_in[3], (long long)N, flagG);
    hipMemsetAsync(flag2, 0, 4, stream);

    // batched f32 conversion
    CvtArgs ca;
    int pre = 0;
    for (int t = 0; t < 15; ++t) {
        ca.src[t] = d_in[fidx[t]]; ca.dst[t] = F[fidx[t]]; ca.n[t] = fsize[t]; ca.fi[t] = fidx[t];
        ca.pre[t] = pre; pre += (fsize[t] + 255) / 256;
    }
    ca.pre[15] = pre;
    k_cvt_all<<<pre, 256, 0, stream>>>(ca, fl);
    k_cvt_bf16<<<(128 * 4096 + 255) / 256, 256, 0, stream>>>(d_in[8], w2bf, 128 * 4096, fl + 8);

    hipMemsetAsync(counts, 0, (size_t)N * 4, stream);
    hipMemsetAsync(qstar, 0, (size_t)(B * 128 + B * 64 + B * 64) * 4, stream);  // qstar+hs+cs contiguous

    k_counts<<<E / 256, 256, 0, stream>>>(d_in[2], flagE, counts, E);
    k_rowptr<<<(B + 1 + 255) / 256, 256, 0, stream>>>(d_in[3], flagG, rowptr, N, B);
    k_lin0<<<N / 4, 256, 0, stream>>>(d_in[0], F[4], F[5], outbuf, fl + 0);
    k1_h1<<<E / 2, 256, 0, stream>>>(d_in[1], F[6], F[7], h1, fl + 1);

    auto gen_W = [&](int c, int ec) {
        dim3 g2(ec / 128, 32);
        k2_wgemm<<<g2, 256, 0, stream>>>(h1, w2bf, F[9], Wbuf, c);
        k_check<<<8 * 4096 / 256, 256, 0, stream>>>((const unsigned short*)Wbuf, h1,
                                                    F[8], F[9], c, ec, flag2);
        dim3 gr(ec / 64, 16);
        k_repair<<<gr, 256, 0, stream>>>(Wbuf, h1, F[8], F[9], c, flag2);
    };

    if (full) gen_W(0, E);
    for (int it = 0; it < 3; ++it) {
        hipMemsetAsync(agg, 0, (size_t)N * 64 * 4, stream);
        if (full) {
            k3_msg<<<E / 4, 256, 0, stream>>>(Wbuf, outbuf, d_in[2], flagE, agg, E, 0);
        } else {
            for (int c = 0; c < E; c += EC) {
                gen_W(c, EC);
                k3_msg<<<EC / 4, 256, 0, stream>>>(Wbuf, outbuf, d_in[2], flagE, agg, c + EC, c);
            }
        }
        k4_gru<<<N / 256, 256, 0, stream>>>(agg, counts, F[10], F[11], F[12], F[13], F[14], outbuf);
    }
    for (int t = 0; t < 3; ++t) {
        k5_lstm<<<B, 256, 0, stream>>>(qstar, hsb, csb, F[15], F[16], F[17], F[18]);
        k5_attn<<<B, 64, 0, stream>>>(outbuf, hsb, rowptr, qstar);
    }
    k_out<<<(out_size + 255) / 256, 256, 0, stream>>>(qstar, outbuf, (float*)d_out,
                                                      B * 128, N * 64, out_size);
}

// Round 8
// 4223.949 us; speedup vs baseline: 2.9810x; 1.0116x over previous
//
#include <hip/hip_runtime.h>
#include <hip/hip_bf16.h>

#define GN 65536
#define GE 131072
#define GB 2048

typedef __attribute__((ext_vector_type(8))) short short8;
typedef __attribute__((ext_vector_type(4))) float floatx4;

static __device__ __forceinline__ float sigm(float x) { return 1.0f / (1.0f + __expf(-x)); }
static __device__ __forceinline__ float bf2f(unsigned short u) {
    union { unsigned int i; float f; } v; v.i = ((unsigned int)u) << 16; return v.f;
}
static __device__ __forceinline__ int geti(const void* p, long long i, int f64) {
    return f64 ? (int)((const long long*)p)[i] : ((const int*)p)[i];
}

// ---- batched per-tensor float dtype detector (one block per tensor) ----
struct DetectArgs { const void* src[17]; int nhalf[17]; int fi[17]; };
__global__ void k_dtype_all(DetectArgs a, int* __restrict__ flags) {
    const unsigned short* p = (const unsigned short*)a.src[blockIdx.x];
    const int n0 = a.nhalf[blockIdx.x];
    const int n = n0 < 16384 ? n0 : 16384;
    __shared__ unsigned int sAny[256], sOr[256];
    unsigned int any = 0, orEven = 0;
    for (int i = threadIdx.x; i < n; i += 256) {
        const unsigned short u = p[i];
        const float av = fabsf(bf2f(u));
        if (!(av <= 1e6f)) any = 1u;
        if ((i & 1) == 0) orEven |= u;
    }
    sAny[threadIdx.x] = any; sOr[threadIdx.x] = orEven;
    __syncthreads();
    for (int s = 128; s > 0; s >>= 1) {
        if (threadIdx.x < s) {
            sAny[threadIdx.x] |= sAny[threadIdx.x + s];
            sOr[threadIdx.x]  |= sOr[threadIdx.x + s];
        }
        __syncthreads();
    }
    if (threadIdx.x == 0) flags[a.fi[blockIdx.x]] = (sAny[0] || sOr[0] == 0u) ? 1 : 0;
}

// int64 detector, sampled
__global__ void k_i64(const unsigned int* __restrict__ p, long long nwords, int* __restrict__ flag) {
    const long long lim = nwords < 16384 ? nwords : 16384;
    __shared__ unsigned int s[256];
    unsigned int acc = 0;
    for (long long w = 1 + 2 * (long long)threadIdx.x; w < lim; w += 512) acc |= p[w];
    s[threadIdx.x] = acc;
    __syncthreads();
    for (int st = 128; st > 0; st >>= 1) {
        if (threadIdx.x < st) s[threadIdx.x] |= s[threadIdx.x + st];
        __syncthreads();
    }
    if (threadIdx.x == 0) *flag = (s[0] == 0u) ? 1 : 0;
}

// ---- batched f32 canonicalization of the 15 small float tensors ----
struct CvtArgs { const void* src[15]; float* dst[15]; int n[15]; int fi[15]; int pre[16]; };
__global__ void k_cvt_all(CvtArgs a, const int* __restrict__ flags) {
    const int b = blockIdx.x;
    int t = 0;
    while (t < 14 && b >= a.pre[t + 1]) ++t;
    const int i = (b - a.pre[t]) * 256 + threadIdx.x;
    if (i >= a.n[t]) return;
    const int f = flags[a.fi[t]];
    a.dst[t][i] = f ? ((const float*)a.src[t])[i] : bf2f(((const unsigned short*)a.src[t])[i]);
}

__global__ void k_cvt_bf16(const void* __restrict__ src, __hip_bfloat16* __restrict__ dst,
                           int n, const int* __restrict__ flag) {
    int i = blockIdx.x * 256 + threadIdx.x;
    if (i >= n) return;
    if (*flag) dst[i] = __float2bfloat16(((const float*)src)[i]);
    else ((unsigned short*)dst)[i] = ((const unsigned short*)src)[i];
}

__global__ void k_counts(const void* __restrict__ eidx, const int* __restrict__ fi64,
                         float* __restrict__ counts, int E_) {
    int e = blockIdx.x * 256 + threadIdx.x;
    if (e < E_) atomicAdd(&counts[geti(eidx, (long long)E_ + e, *fi64)], 1.0f);
}

__global__ void k_rowptr(const void* __restrict__ gi, const int* __restrict__ fi64,
                         int* __restrict__ rowptr, int N_, int B_) {
    int g = blockIdx.x * 256 + threadIdx.x;
    if (g > B_) return;
    const int f64 = *fi64;
    int lo = 0, hi = N_;
    while (lo < hi) { int mid = (lo + hi) >> 1; if (geti(gi, mid, f64) < g) lo = mid + 1; else hi = mid; }
    rowptr[g] = lo;
}

// lin0: out = relu(nf @ lin0_w + b)
__global__ __launch_bounds__(256) void k_lin0(const void* __restrict__ nf_raw,
                                              const float* __restrict__ w,
                                              const float* __restrict__ b,
                                              float* __restrict__ out,
                                              const int* __restrict__ flag) {
    const int ln = threadIdx.x >> 6;
    const int d = threadIdx.x & 63;
    const int n = blockIdx.x * 4 + ln;
    const int isf32 = *flag;
    __shared__ float s_nf[4][76];
    const size_t base = (size_t)n * 75;
    s_nf[ln][d] = isf32 ? ((const float*)nf_raw)[base + d] : bf2f(((const unsigned short*)nf_raw)[base + d]);
    if (d < 11) s_nf[ln][64 + d] = isf32 ? ((const float*)nf_raw)[base + 64 + d]
                                         : bf2f(((const unsigned short*)nf_raw)[base + 64 + d]);
    __syncthreads();
    float acc = b[d];
    #pragma unroll
    for (int i = 0; i < 75; ++i) acc += s_nf[ln][i] * w[i * 64 + d];
    out[(size_t)n * 64 + d] = fmaxf(acc, 0.0f);
}

// h1 = relu(ef @ w1 + b1) -> bf16
__global__ __launch_bounds__(256) void k1_h1(const void* __restrict__ ef_raw,
                                             const float* __restrict__ w1,
                                             const float* __restrict__ b1,
                                             __hip_bfloat16* __restrict__ h1,
                                             const int* __restrict__ flag) {
    const int le = threadIdx.x >> 7;
    const int j = threadIdx.x & 127;
    const int e = blockIdx.x * 2 + le;
    const int isf32 = *flag;
    __shared__ float efs[2][16];
    if (j < 16) {
        const size_t idx = (size_t)e * 16 + j;
        efs[le][j] = isf32 ? ((const float*)ef_raw)[idx] : bf2f(((const unsigned short*)ef_raw)[idx]);
    }
    __syncthreads();
    float acc = b1[j];
    #pragma unroll
    for (int i = 0; i < 16; ++i) acc += efs[le][i] * w1[i * 128 + j];
    h1[(size_t)e * 128 + j] = __float2bfloat16(fmaxf(acc, 0.0f));
}

// FUSED NNConv message pass: per block of 64 edges, compute W on the fly
// (MFMA, never materialized) and accumulate msg[e,f] = sum_d y[e,d]*W[e,d,f]
// in registers; single atomic scatter into agg[dst].
// C-layout per lane is n0-invariant: element (mt,nt,r) always maps to
// edge = wm+mt*16+quad*4+r, f = nt*16+lr; d = (n0+wn)>>6 is wave-uniform.
__global__ __launch_bounds__(256) void k23_fused(const __hip_bfloat16* __restrict__ h1,
                                                 const __hip_bfloat16* __restrict__ w2,
                                                 const float* __restrict__ b2,
                                                 const float* __restrict__ out,
                                                 const void* __restrict__ eidx,
                                                 const int* __restrict__ fi64,
                                                 float* __restrict__ agg) {
    __shared__ __hip_bfloat16 As[64][136];   // h1 tile [edge][k], +8 pad (16B rows)
    __shared__ __hip_bfloat16 Bs[128][72];   // w2 tile [n][k], transposed
    __shared__ float ylds[64][68];           // y = out[src] [edge][d], 16B-aligned rows
    __shared__ int sidx[128];                // src[0:64] | dst[64:128]
    const int tid = threadIdx.x;
    const int e0 = blockIdx.x * 64;

    if (tid < 64) sidx[tid] = geti(eidx, e0 + tid, *fi64);
    else if (tid < 128) sidx[tid] = geti(eidx, (long long)GE + e0 + (tid - 64), *fi64);
    #pragma unroll
    for (int i = 0; i < 4; ++i) {            // As: 64 rows x 128 k
        int chunk = i * 256 + tid;
        int r = chunk >> 4, c = (chunk & 15) * 8;
        *(int4*)(&As[r][c]) = *(const int4*)(h1 + (size_t)(e0 + r) * 128 + c);
    }
    __syncthreads();                          // sidx ready
    {                                         // gather y: thread t -> edge t>>2, 16 d's
        const int e = tid >> 2, d0 = (tid & 3) * 16;
        const float* srow = out + (size_t)sidx[e] * 64 + d0;
        #pragma unroll
        for (int j = 0; j < 4; ++j)
            *(float4*)(&ylds[e][d0 + j * 4]) = *(const float4*)(srow + j * 4);
    }

    const int wave = tid >> 6, lane = tid & 63;
    const int wm = (wave >> 1) * 32;          // 2 waves on edges
    const int wn = (wave & 1) * 64;           // 2 waves on cols
    const int lr = lane & 15, quad = lane >> 4;
    float msum[2][4][4] = {};                 // [mt][nt][r]

    for (int n0 = 0; n0 < 4096; n0 += 128) {
        floatx4 acc[2][4] = {};
        const int dcur = (n0 + wn) >> 6;      // wave-uniform d for this tile
        #pragma unroll
        for (int kst = 0; kst < 2; ++kst) {
            const int kb = kst * 64;
            #pragma unroll
            for (int i = 0; i < 4; ++i) {     // Bs: 128 n x 64 k (transpose-on-store)
                int chunk = i * 256 + tid;
                int k = chunk >> 4, c = (chunk & 15) * 8;
                int4 v = *(const int4*)(w2 + (size_t)(kb + k) * 4096 + n0 + c);
                const __hip_bfloat16* pv = (const __hip_bfloat16*)&v;
                #pragma unroll
                for (int jj = 0; jj < 8; ++jj) Bs[c + jj][k] = pv[jj];
            }
            __syncthreads();
            #pragma unroll
            for (int ks = 0; ks < 64; ks += 32) {
                short8 af[2], bfr[4];
                #pragma unroll
                for (int mt = 0; mt < 2; ++mt)
                    af[mt] = *(const short8*)(&As[wm + mt * 16 + lr][kb + ks + quad * 8]);
                #pragma unroll
                for (int nt = 0; nt < 4; ++nt)
                    bfr[nt] = *(const short8*)(&Bs[wn + nt * 16 + lr][ks + quad * 8]);
                #pragma unroll
                for (int mt = 0; mt < 2; ++mt)
                    #pragma unroll
                    for (int nt = 0; nt < 4; ++nt)
                        acc[mt][nt] = __builtin_amdgcn_mfma_f32_16x16x32_bf16(af[mt], bfr[nt], acc[mt][nt], 0, 0, 0);
            }
            __syncthreads();                  // Bs consumed before next overwrite
        }
        // epilogue: msum += y[edge][dcur] * (acc + b2[n])
        #pragma unroll
        for (int nt = 0; nt < 4; ++nt) {
            const float b2v = b2[n0 + wn + nt * 16 + lr];
            #pragma unroll
            for (int mt = 0; mt < 2; ++mt) {
                #pragma unroll
                for (int r = 0; r < 4; ++r) {
                    const int row = wm + mt * 16 + quad * 4 + r;
                    msum[mt][nt][r] = fmaf(ylds[row][dcur], acc[mt][nt][r] + b2v, msum[mt][nt][r]);
                }
            }
        }
    }
    // scatter: each n-wave holds the partial over its d's; atomicAdd combines
    #pragma unroll
    for (int mt = 0; mt < 2; ++mt)
        #pragma unroll
        for (int r = 0; r < 4; ++r) {
            const int row = wm + mt * 16 + quad * 4 + r;
            const int dn = sidx[64 + row];
            #pragma unroll
            for (int nt = 0; nt < 4; ++nt)
                atomicAdd(&agg[(size_t)dn * 64 + nt * 16 + lr], msum[mt][nt][r]);
        }
}

// GRU: wave = 64 nodes (lane=node); wave-uniform weight reads (SMEM);
// results staged through LDS slab -> coalesced writeback (kills the 16x
// write amplification seen in r7: WRITE 265 MB -> 17 MB).
__global__ __launch_bounds__(256) void k4_gru(const float* __restrict__ agg,
                                              const float* __restrict__ counts,
                                              const float* __restrict__ cbias,
                                              const float* __restrict__ w_ih,
                                              const float* __restrict__ w_hh,
                                              const float* __restrict__ b_ih,
                                              const float* __restrict__ b_hh,
                                              float* __restrict__ out) {
    const int wv = threadIdx.x >> 6;
    const int lane = threadIdx.x & 63;
    const int nb0 = blockIdx.x * 256 + wv * 64;
    __shared__ float slab_all[4][64][65];
    float (*slab)[65] = slab_all[wv];

    for (int r = 0; r < 64; ++r)
        slab[r][lane] = agg[(size_t)(nb0 + r) * 64 + lane];
    const float rcnt = 1.0f / fmaxf(counts[nb0 + lane], 1.0f);
    __syncthreads();
    float m[64];
    #pragma unroll
    for (int k = 0; k < 64; ++k)
        m[k] = fmaxf(slab[lane][k] * rcnt + cbias[k], 0.0f);
    __syncthreads();
    for (int r = 0; r < 64; ++r)
        slab[r][lane] = out[(size_t)(nb0 + r) * 64 + lane];
    __syncthreads();
    float h[64];
    #pragma unroll
    for (int k = 0; k < 64; ++k) h[k] = slab[lane][k];

    #pragma unroll 1
    for (int d = 0; d < 64; ++d) {
        float a0 = b_ih[d], a1 = b_ih[64 + d], a2 = b_ih[128 + d];
        float g0 = b_hh[d], g1 = b_hh[64 + d], g2 = b_hh[128 + d];
        const float* wi0 = w_ih + (size_t)d * 64;
        const float* wi1 = w_ih + (size_t)(64 + d) * 64;
        const float* wi2 = w_ih + (size_t)(128 + d) * 64;
        const float* wh0 = w_hh + (size_t)d * 64;
        const float* wh1 = w_hh + (size_t)(64 + d) * 64;
        const float* wh2 = w_hh + (size_t)(128 + d) * 64;
        #pragma unroll
        for (int k = 0; k < 64; ++k) {
            a0 = fmaf(m[k], wi0[k], a0);
            a1 = fmaf(m[k], wi1[k], a1);
            a2 = fmaf(m[k], wi2[k], a2);
            g0 = fmaf(h[k], wh0[k], g0);
            g1 = fmaf(h[k], wh1[k], g1);
            g2 = fmaf(h[k], wh2[k], g2);
        }
        const float r_ = sigm(a0 + g0);
        const float z  = sigm(a1 + g1);
        const float nn = tanhf(a2 + r_ * g2);
        const float hd = slab[lane][d];       // old h[d] (lane-private row)
        slab[lane][d] = (1.0f - z) * nn + z * hd;   // stage h_new in place
    }
    // coalesced writeback via transpose (lane-private rows -> columns)
    for (int r = 0; r < 64; ++r)
        out[(size_t)(nb0 + r) * 64 + lane] = slab[r][lane];
}

__global__ __launch_bounds__(256) void k5_lstm(float* __restrict__ qstar,
                                               float* __restrict__ hs, float* __restrict__ cs,
                                               const float* __restrict__ w_ih,
                                               const float* __restrict__ w_hh,
                                               const float* __restrict__ b_ih,
                                               const float* __restrict__ b_hh) {
    const int g = blockIdx.x;
    const int j = threadIdx.x;
    __shared__ float qs[128], hv[64], gates[256];
    if (j < 128) qs[j] = qstar[(size_t)g * 128 + j];
    else if (j < 192) hv[j - 128] = hs[(size_t)g * 64 + (j - 128)];
    __syncthreads();
    float acc = b_ih[j] + b_hh[j];
    for (int k4 = 0; k4 < 128; k4 += 4) {
        float4 v = *(const float4*)(w_ih + (size_t)j * 128 + k4);
        const float* pv = (const float*)&v;
        #pragma unroll
        for (int t = 0; t < 4; ++t) acc += qs[k4 + t] * pv[t];
    }
    for (int k4 = 0; k4 < 64; k4 += 4) {
        float4 v = *(const float4*)(w_hh + (size_t)j * 64 + k4);
        const float* pv = (const float*)&v;
        #pragma unroll
        for (int t = 0; t < 4; ++t) acc += hv[k4 + t] * pv[t];
    }
    gates[j] = acc;
    __syncthreads();
    if (j < 64) {
        const float ig = sigm(gates[j]);
        const float fg = sigm(gates[64 + j]);
        const float gg = tanhf(gates[128 + j]);
        const float og = sigm(gates[192 + j]);
        const float c = fg * cs[(size_t)g * 64 + j] + ig * gg;
        const float h = og * tanhf(c);
        cs[(size_t)g * 64 + j] = c;
        hs[(size_t)g * 64 + j] = h;
        qstar[(size_t)g * 128 + j] = h;
    }
}

// Set2Set attention: single-pass online softmax, wave per graph
__global__ __launch_bounds__(64) void k5_attn(const float* __restrict__ out,
                                              const float* __restrict__ hs,
                                              const int* __restrict__ rowptr,
                                              float* __restrict__ qstar) {
    const int g = blockIdx.x;
    const int lane = threadIdx.x;
    const float q = hs[(size_t)g * 64 + lane];
    const int start = rowptr[g], end = rowptr[g + 1];
    float m = -3.4e38f, S = 0.0f, racc = 0.0f;
    for (int n = start; n < end; ++n) {
        const float ov = out[(size_t)n * 64 + lane];
        float p = ov * q;
        #pragma unroll
        for (int off = 1; off < 64; off <<= 1) p += __shfl_xor(p, off);
        if (p > m) {
            const float sc = __expf(m - p);
            S = S * sc + 1.0f;
            racc = racc * sc + ov;
            m = p;
        } else {
            const float w = __expf(p - m);
            S += w;
            racc += w * ov;
        }
    }
    qstar[(size_t)g * 128 + 64 + lane] = racc / (S + 1e-16f);
}

__global__ void k_out(const float* __restrict__ qstar, const float* __restrict__ outb,
                      float* __restrict__ dst, int nq, int nfeat, int out_n) {
    int i = blockIdx.x * 256 + threadIdx.x;
    if (i >= out_n) return;
    float v = 0.0f;
    if (i < nq) v = qstar[i];
    else if (i - nq < nfeat) v = outb[i - nq];
    dst[i] = v;
}

extern "C" void kernel_launch(void* const* d_in, const int* in_sizes, int n_in,
                              void* d_out, int out_size, void* d_ws, size_t ws_size,
                              hipStream_t stream) {
    constexpr int N = GN, E = GE, B = GB;

    char* ws = (char*)d_ws;
    size_t off = 0;
    auto alloc = [&](size_t bytes) { size_t o = off; off = (off + bytes + 255) & ~(size_t)255; return o; };

    int*   fl     = (int*)  (ws + alloc(19 * 4));
    int*   flagE  = (int*)  (ws + alloc(256));
    int*   flagG  = (int*)  (ws + alloc(256));
    float* counts = (float*)(ws + alloc((size_t)N * 4));
    int*   rowptr = (int*)  (ws + alloc((size_t)(B + 1) * 4));
    float* outbuf = (float*)(ws + alloc((size_t)N * 64 * 4));
    float* agg    = (float*)(ws + alloc((size_t)N * 64 * 4));
    float* qstar  = (float*)(ws + alloc((size_t)B * 128 * 4));   // qstar+hs+cs contiguous
    float* hsb    = (float*)(ws + alloc((size_t)B * 64 * 4));
    float* csb    = (float*)(ws + alloc((size_t)B * 64 * 4));
    __hip_bfloat16* h1   = (__hip_bfloat16*)(ws + alloc((size_t)E * 128 * 2));
    __hip_bfloat16* w2bf = (__hip_bfloat16*)(ws + alloc((size_t)128 * 4096 * 2));

    const int fidx[15]  = {4, 5, 6, 7, 8, 9, 10, 11, 12, 13, 14, 15, 16, 17, 18};
    const int fsize[15] = {75 * 64, 64, 16 * 128, 128, 128 * 4096, 4096, 64,
                           192 * 64, 192 * 64, 192, 192, 256 * 128, 256 * 64, 256, 256};
    float* F[19] = {};
    for (int t = 0; t < 15; ++t) F[fidx[t]] = (float*)(ws + alloc((size_t)fsize[t] * 4));

    // batched dtype detection
    DetectArgs da;
    da.src[0] = d_in[0]; da.nhalf[0] = N * 75; da.fi[0] = 0;
    da.src[1] = d_in[1]; da.nhalf[1] = E * 16; da.fi[1] = 1;
    for (int t = 0; t < 15; ++t) { da.src[2 + t] = d_in[fidx[t]]; da.nhalf[2 + t] = fsize[t]; da.fi[2 + t] = fidx[t]; }
    k_dtype_all<<<17, 256, 0, stream>>>(da, fl);
    k_i64<<<1, 256, 0, stream>>>((const unsigned int*)d_in[2], (long long)2 * E, flagE);
    k_i64<<<1, 256, 0, stream>>>((const unsigned int*)d_in[3], (long long)N, flagG);

    // batched f32 conversion
    CvtArgs ca;
    int pre = 0;
    for (int t = 0; t < 15; ++t) {
        ca.src[t] = d_in[fidx[t]]; ca.dst[t] = F[fidx[t]]; ca.n[t] = fsize[t]; ca.fi[t] = fidx[t];
        ca.pre[t] = pre; pre += (fsize[t] + 255) / 256;
    }
    ca.pre[15] = pre;
    k_cvt_all<<<pre, 256, 0, stream>>>(ca, fl);
    k_cvt_bf16<<<(128 * 4096 + 255) / 256, 256, 0, stream>>>(d_in[8], w2bf, 128 * 4096, fl + 8);

    hipMemsetAsync(counts, 0, (size_t)N * 4, stream);
    hipMemsetAsync(qstar, 0, (size_t)(B * 128 + B * 64 + B * 64) * 4, stream);

    k_counts<<<E / 256, 256, 0, stream>>>(d_in[2], flagE, counts, E);
    k_rowptr<<<(B + 1 + 255) / 256, 256, 0, stream>>>(d_in[3], flagG, rowptr, N, B);
    k_lin0<<<N / 4, 256, 0, stream>>>(d_in[0], F[4], F[5], outbuf, fl + 0);
    k1_h1<<<E / 2, 256, 0, stream>>>(d_in[1], F[6], F[7], h1, fl + 1);

    for (int it = 0; it < 3; ++it) {
        hipMemsetAsync(agg, 0, (size_t)N * 64 * 4, stream);
        k23_fused<<<E / 64, 256, 0, stream>>>(h1, w2bf, F[9], outbuf, d_in[2], flagE, agg);
        k4_gru<<<N / 256, 256, 0, stream>>>(agg, counts, F[10], F[11], F[12], F[13], F[14], outbuf);
    }
    for (int t = 0; t < 3; ++t) {
        k5_lstm<<<B, 256, 0, stream>>>(qstar, hsb, csb, F[15], F[16], F[17], F[18]);
        k5_attn<<<B, 64, 0, stream>>>(outbuf, hsb, rowptr, qstar);
    }
    k_out<<<(out_size + 255) / 256, 256, 0, stream>>>(qstar, outbuf, (float*)d_out,
                                                      B * 128, N * 64, out_size);
}

// Round 9
// 1997.545 us; speedup vs baseline: 6.3036x; 2.1146x over previous
//
#include <hip/hip_runtime.h>
#include <hip/hip_bf16.h>

#define GN 65536
#define GE 131072
#define GB 2048

typedef __attribute__((ext_vector_type(8))) short short8;
typedef __attribute__((ext_vector_type(4))) float floatx4;

static __device__ __forceinline__ float sigm(float x) { return 1.0f / (1.0f + __expf(-x)); }
static __device__ __forceinline__ float bf2f(unsigned short u) {
    union { unsigned int i; float f; } v; v.i = ((unsigned int)u) << 16; return v.f;
}
static __device__ __forceinline__ int geti(const void* p, long long i, int f64) {
    return f64 ? (int)((const long long*)p)[i] : ((const int*)p)[i];
}

// ---- batched per-tensor float dtype detector (one block per tensor) ----
struct DetectArgs { const void* src[17]; int nhalf[17]; int fi[17]; };
__global__ void k_dtype_all(DetectArgs a, int* __restrict__ flags) {
    const unsigned short* p = (const unsigned short*)a.src[blockIdx.x];
    const int n0 = a.nhalf[blockIdx.x];
    const int n = n0 < 16384 ? n0 : 16384;
    __shared__ unsigned int sAny[256], sOr[256];
    unsigned int any = 0, orEven = 0;
    for (int i = threadIdx.x; i < n; i += 256) {
        const unsigned short u = p[i];
        const float av = fabsf(bf2f(u));
        if (!(av <= 1e6f)) any = 1u;
        if ((i & 1) == 0) orEven |= u;
    }
    sAny[threadIdx.x] = any; sOr[threadIdx.x] = orEven;
    __syncthreads();
    for (int s = 128; s > 0; s >>= 1) {
        if (threadIdx.x < s) {
            sAny[threadIdx.x] |= sAny[threadIdx.x + s];
            sOr[threadIdx.x]  |= sOr[threadIdx.x + s];
        }
        __syncthreads();
    }
    if (threadIdx.x == 0) flags[a.fi[blockIdx.x]] = (sAny[0] || sOr[0] == 0u) ? 1 : 0;
}

// int64 detector, sampled
__global__ void k_i64(const unsigned int* __restrict__ p, long long nwords, int* __restrict__ flag) {
    const long long lim = nwords < 16384 ? nwords : 16384;
    __shared__ unsigned int s[256];
    unsigned int acc = 0;
    for (long long w = 1 + 2 * (long long)threadIdx.x; w < lim; w += 512) acc |= p[w];
    s[threadIdx.x] = acc;
    __syncthreads();
    for (int st = 128; st > 0; st >>= 1) {
        if (threadIdx.x < st) s[threadIdx.x] |= s[threadIdx.x + st];
        __syncthreads();
    }
    if (threadIdx.x == 0) *flag = (s[0] == 0u) ? 1 : 0;
}

// ---- batched f32 canonicalization of the 15 small float tensors ----
struct CvtArgs { const void* src[15]; float* dst[15]; int n[15]; int fi[15]; int pre[16]; };
__global__ void k_cvt_all(CvtArgs a, const int* __restrict__ flags) {
    const int b = blockIdx.x;
    int t = 0;
    while (t < 14 && b >= a.pre[t + 1]) ++t;
    const int i = (b - a.pre[t]) * 256 + threadIdx.x;
    if (i >= a.n[t]) return;
    const int f = flags[a.fi[t]];
    a.dst[t][i] = f ? ((const float*)a.src[t])[i] : bf2f(((const unsigned short*)a.src[t])[i]);
}

// transpose w2 [128][4096] -> w2T bf16 [4096][128], read polymorphic & coalesced
// (writes scattered 16B — one-shot 32MB, acceptable)
__global__ __launch_bounds__(256) void k_t2(const void* __restrict__ src,
                                            __hip_bfloat16* __restrict__ w2T,
                                            const int* __restrict__ flag) {
    const int idx = blockIdx.x * 256 + threadIdx.x;   // 0..65535
    const int kb8 = idx >> 12;                        // 16 k-groups of 8
    const int n = idx & 4095;
    const int isf32 = *flag;
    short8 v;
    #pragma unroll
    for (int j = 0; j < 8; ++j) {
        const size_t si = (size_t)(kb8 * 8 + j) * 4096 + n;
        const float f = isf32 ? ((const float*)src)[si] : bf2f(((const unsigned short*)src)[si]);
        const __hip_bfloat16 b = __float2bfloat16(f);
        v[j] = *(const short*)&b;
    }
    *(short8*)(w2T + (size_t)n * 128 + kb8 * 8) = v;
}

// repack GRU weights into contiguous per-d blocks: wpk[d][6][64]
// order per d: wi_r, wi_z, wi_n, wh_r, wh_z, wh_n
__global__ void k_gpack(const float* __restrict__ w_ih, const float* __restrict__ w_hh,
                        float* __restrict__ wpk) {
    int idx = blockIdx.x * 256 + threadIdx.x;         // d*384 + g*64 + k
    if (idx >= 64 * 384) return;
    const int d = idx / 384, rem = idx % 384, g = rem >> 6, k = rem & 63;
    wpk[idx] = (g < 3) ? w_ih[(g * 64 + d) * 64 + k] : w_hh[((g - 3) * 64 + d) * 64 + k];
}

__global__ void k_counts(const void* __restrict__ eidx, const int* __restrict__ fi64,
                         float* __restrict__ counts, int E_) {
    int e = blockIdx.x * 256 + threadIdx.x;
    if (e < E_) atomicAdd(&counts[geti(eidx, (long long)E_ + e, *fi64)], 1.0f);
}

__global__ void k_rowptr(const void* __restrict__ gi, const int* __restrict__ fi64,
                         int* __restrict__ rowptr, int N_, int B_) {
    int g = blockIdx.x * 256 + threadIdx.x;
    if (g > B_) return;
    const int f64 = *fi64;
    int lo = 0, hi = N_;
    while (lo < hi) { int mid = (lo + hi) >> 1; if (geti(gi, mid, f64) < g) lo = mid + 1; else hi = mid; }
    rowptr[g] = lo;
}

// lin0: out = relu(nf @ lin0_w + b)
__global__ __launch_bounds__(256) void k_lin0(const void* __restrict__ nf_raw,
                                              const float* __restrict__ w,
                                              const float* __restrict__ b,
                                              float* __restrict__ out,
                                              const int* __restrict__ flag) {
    const int ln = threadIdx.x >> 6;
    const int d = threadIdx.x & 63;
    const int n = blockIdx.x * 4 + ln;
    const int isf32 = *flag;
    __shared__ float s_nf[4][76];
    const size_t base = (size_t)n * 75;
    s_nf[ln][d] = isf32 ? ((const float*)nf_raw)[base + d] : bf2f(((const unsigned short*)nf_raw)[base + d]);
    if (d < 11) s_nf[ln][64 + d] = isf32 ? ((const float*)nf_raw)[base + 64 + d]
                                         : bf2f(((const unsigned short*)nf_raw)[base + 64 + d]);
    __syncthreads();
    float acc = b[d];
    #pragma unroll
    for (int i = 0; i < 75; ++i) acc += s_nf[ln][i] * w[i * 64 + d];
    out[(size_t)n * 64 + d] = fmaxf(acc, 0.0f);
}

// h1 = relu(ef @ w1 + b1) -> bf16
__global__ __launch_bounds__(256) void k1_h1(const void* __restrict__ ef_raw,
                                             const float* __restrict__ w1,
                                             const float* __restrict__ b1,
                                             __hip_bfloat16* __restrict__ h1,
                                             const int* __restrict__ flag) {
    const int le = threadIdx.x >> 7;
    const int j = threadIdx.x & 127;
    const int e = blockIdx.x * 2 + le;
    const int isf32 = *flag;
    __shared__ float efs[2][16];
    if (j < 16) {
        const size_t idx = (size_t)e * 16 + j;
        efs[le][j] = isf32 ? ((const float*)ef_raw)[idx] : bf2f(((const unsigned short*)ef_raw)[idx]);
    }
    __syncthreads();
    float acc = b1[j];
    #pragma unroll
    for (int i = 0; i < 16; ++i) acc += efs[le][i] * w1[i * 128 + j];
    h1[(size_t)e * 128 + j] = __float2bfloat16(fmaxf(acc, 0.0f));
}

// FUSED NNConv: per 64-edge block compute W on the fly (MFMA) and reduce
// msg[e,f] = sum_d y[e,d]*W[e,d,f] in registers; atomic scatter to agg[dst].
// v2: Bs staged from PRE-TRANSPOSED w2T with int4s (m97 pattern) — kills the
// 5.3e8 LDS bank conflicts of the r8 scalar transpose-on-store.
__global__ __launch_bounds__(256) void k23_fused(const __hip_bfloat16* __restrict__ h1,
                                                 const __hip_bfloat16* __restrict__ w2T,
                                                 const float* __restrict__ b2,
                                                 const float* __restrict__ out,
                                                 const void* __restrict__ eidx,
                                                 const int* __restrict__ fi64,
                                                 float* __restrict__ agg) {
    __shared__ __hip_bfloat16 As[64][136];   // h1 tile [edge][k], +8 pad
    __shared__ __hip_bfloat16 Bs[128][72];   // w2T tile [n][k], +8 pad
    __shared__ float ylds[64][68];           // y = out[src]
    __shared__ int sidx[128];
    const int tid = threadIdx.x;
    const int e0 = blockIdx.x * 64;

    if (tid < 64) sidx[tid] = geti(eidx, e0 + tid, *fi64);
    else if (tid < 128) sidx[tid] = geti(eidx, (long long)GE + e0 + (tid - 64), *fi64);
    #pragma unroll
    for (int i = 0; i < 4; ++i) {
        int chunk = i * 256 + tid;
        int r = chunk >> 4, c = (chunk & 15) * 8;
        *(int4*)(&As[r][c]) = *(const int4*)(h1 + (size_t)(e0 + r) * 128 + c);
    }
    __syncthreads();
    {
        const int e = tid >> 2, d0 = (tid & 3) * 16;
        const float* srow = out + (size_t)sidx[e] * 64 + d0;
        #pragma unroll
        for (int j = 0; j < 4; ++j)
            *(float4*)(&ylds[e][d0 + j * 4]) = *(const float4*)(srow + j * 4);
    }

    const int wave = tid >> 6, lane = tid & 63;
    const int wm = (wave >> 1) * 32;
    const int wn = (wave & 1) * 64;
    const int lr = lane & 15, quad = lane >> 4;
    float msum[2][4][4] = {};

    for (int n0 = 0; n0 < 4096; n0 += 128) {
        floatx4 acc[2][4] = {};
        const int dcur = (n0 + wn) >> 6;
        #pragma unroll
        for (int kst = 0; kst < 2; ++kst) {
            const int kb = kst * 64;
            #pragma unroll
            for (int i = 0; i < 4; ++i) {    // Bs: 128 n-rows x 64 k, int4 (conflict-free)
                int chunk = i * 256 + tid;
                int r = chunk >> 3, c = (chunk & 7) * 8;
                *(int4*)(&Bs[r][c]) = *(const int4*)(w2T + (size_t)(n0 + r) * 128 + kb + c);
            }
            __syncthreads();
            #pragma unroll
            for (int ks = 0; ks < 64; ks += 32) {
                short8 af[2], bfr[4];
                #pragma unroll
                for (int mt = 0; mt < 2; ++mt)
                    af[mt] = *(const short8*)(&As[wm + mt * 16 + lr][kb + ks + quad * 8]);
                #pragma unroll
                for (int nt = 0; nt < 4; ++nt)
                    bfr[nt] = *(const short8*)(&Bs[wn + nt * 16 + lr][ks + quad * 8]);
                #pragma unroll
                for (int mt = 0; mt < 2; ++mt)
                    #pragma unroll
                    for (int nt = 0; nt < 4; ++nt)
                        acc[mt][nt] = __builtin_amdgcn_mfma_f32_16x16x32_bf16(af[mt], bfr[nt], acc[mt][nt], 0, 0, 0);
            }
            __syncthreads();
        }
        #pragma unroll
        for (int nt = 0; nt < 4; ++nt) {
            const float b2v = b2[n0 + wn + nt * 16 + lr];
            #pragma unroll
            for (int mt = 0; mt < 2; ++mt) {
                #pragma unroll
                for (int r = 0; r < 4; ++r) {
                    const int row = wm + mt * 16 + quad * 4 + r;
                    msum[mt][nt][r] = fmaf(ylds[row][dcur], acc[mt][nt][r] + b2v, msum[mt][nt][r]);
                }
            }
        }
    }
    #pragma unroll
    for (int mt = 0; mt < 2; ++mt)
        #pragma unroll
        for (int r = 0; r < 4; ++r) {
            const int row = wm + mt * 16 + quad * 4 + r;
            const int dn = sidx[64 + row];
            #pragma unroll
            for (int nt = 0; nt < 4; ++nt)
                atomicAdd(&agg[(size_t)dn * 64 + nt * 16 + lr], msum[mt][nt][r]);
        }
}

// GRU: wave = 64 nodes (lane=node); wave-uniform weight reads from the packed
// contiguous wpk[d][6][64] (one 1.5KB scalar burst per d); LDS-staged
// transpose loads + coalesced writeback.
__global__ __launch_bounds__(256) void k4_gru(const float* __restrict__ agg,
                                              const float* __restrict__ counts,
                                              const float* __restrict__ cbias,
                                              const float* __restrict__ wpk,
                                              const float* __restrict__ b_ih,
                                              const float* __restrict__ b_hh,
                                              float* __restrict__ out) {
    const int wv = threadIdx.x >> 6;
    const int lane = threadIdx.x & 63;
    const int nb0 = blockIdx.x * 256 + wv * 64;
    __shared__ float slab_all[4][64][65];
    float (*slab)[65] = slab_all[wv];

    for (int r = 0; r < 64; ++r)
        slab[r][lane] = agg[(size_t)(nb0 + r) * 64 + lane];
    const float rcnt = 1.0f / fmaxf(counts[nb0 + lane], 1.0f);
    __syncthreads();
    float m[64];
    #pragma unroll
    for (int k = 0; k < 64; ++k)
        m[k] = fmaxf(slab[lane][k] * rcnt + cbias[k], 0.0f);
    __syncthreads();
    for (int r = 0; r < 64; ++r)
        slab[r][lane] = out[(size_t)(nb0 + r) * 64 + lane];
    __syncthreads();
    float h[64];
    #pragma unroll
    for (int k = 0; k < 64; ++k) h[k] = slab[lane][k];

    #pragma unroll 1
    for (int d = 0; d < 64; ++d) {
        const float* wr = wpk + d * 384;
        float a0 = b_ih[d], a1 = b_ih[64 + d], a2 = b_ih[128 + d];
        float g0 = b_hh[d], g1 = b_hh[64 + d], g2 = b_hh[128 + d];
        #pragma unroll
        for (int k = 0; k < 64; ++k) {
            a0 = fmaf(m[k], wr[k], a0);
            a1 = fmaf(m[k], wr[64 + k], a1);
            a2 = fmaf(m[k], wr[128 + k], a2);
            g0 = fmaf(h[k], wr[192 + k], g0);
            g1 = fmaf(h[k], wr[256 + k], g1);
            g2 = fmaf(h[k], wr[320 + k], g2);
        }
        const float r_ = sigm(a0 + g0);
        const float z  = sigm(a1 + g1);
        const float nn = tanhf(a2 + r_ * g2);
        const float hd = slab[lane][d];
        slab[lane][d] = (1.0f - z) * nn + z * hd;
    }
    for (int r = 0; r < 64; ++r)
        out[(size_t)(nb0 + r) * 64 + lane] = slab[r][lane];
}

__global__ __launch_bounds__(256) void k5_lstm(float* __restrict__ qstar,
                                               float* __restrict__ hs, float* __restrict__ cs,
                                               const float* __restrict__ w_ih,
                                               const float* __restrict__ w_hh,
                                               const float* __restrict__ b_ih,
                                               const float* __restrict__ b_hh) {
    const int g = blockIdx.x;
    const int j = threadIdx.x;
    __shared__ float qs[128], hv[64], gates[256];
    if (j < 128) qs[j] = qstar[(size_t)g * 128 + j];
    else if (j < 192) hv[j - 128] = hs[(size_t)g * 64 + (j - 128)];
    __syncthreads();
    float acc = b_ih[j] + b_hh[j];
    for (int k4 = 0; k4 < 128; k4 += 4) {
        float4 v = *(const float4*)(w_ih + (size_t)j * 128 + k4);
        const float* pv = (const float*)&v;
        #pragma unroll
        for (int t = 0; t < 4; ++t) acc += qs[k4 + t] * pv[t];
    }
    for (int k4 = 0; k4 < 64; k4 += 4) {
        float4 v = *(const float4*)(w_hh + (size_t)j * 64 + k4);
        const float* pv = (const float*)&v;
        #pragma unroll
        for (int t = 0; t < 4; ++t) acc += hv[k4 + t] * pv[t];
    }
    gates[j] = acc;
    __syncthreads();
    if (j < 64) {
        const float ig = sigm(gates[j]);
        const float fg = sigm(gates[64 + j]);
        const float gg = tanhf(gates[128 + j]);
        const float og = sigm(gates[192 + j]);
        const float c = fg * cs[(size_t)g * 64 + j] + ig * gg;
        const float h = og * tanhf(c);
        cs[(size_t)g * 64 + j] = c;
        hs[(size_t)g * 64 + j] = h;
        qstar[(size_t)g * 128 + j] = h;
    }
}

// Set2Set attention: single-pass online softmax, wave per graph
__global__ __launch_bounds__(64) void k5_attn(const float* __restrict__ out,
                                              const float* __restrict__ hs,
                                              const int* __restrict__ rowptr,
                                              float* __restrict__ qstar) {
    const int g = blockIdx.x;
    const int lane = threadIdx.x;
    const float q = hs[(size_t)g * 64 + lane];
    const int start = rowptr[g], end = rowptr[g + 1];
    float m = -3.4e38f, S = 0.0f, racc = 0.0f;
    for (int n = start; n < end; ++n) {
        const float ov = out[(size_t)n * 64 + lane];
        float p = ov * q;
        #pragma unroll
        for (int off = 1; off < 64; off <<= 1) p += __shfl_xor(p, off);
        if (p > m) {
            const float sc = __expf(m - p);
            S = S * sc + 1.0f;
            racc = racc * sc + ov;
            m = p;
        } else {
            const float w = __expf(p - m);
            S += w;
            racc += w * ov;
        }
    }
    qstar[(size_t)g * 128 + 64 + lane] = racc / (S + 1e-16f);
}

__global__ void k_out(const float* __restrict__ qstar, const float* __restrict__ outb,
                      float* __restrict__ dst, int nq, int nfeat, int out_n) {
    int i = blockIdx.x * 256 + threadIdx.x;
    if (i >= out_n) return;
    float v = 0.0f;
    if (i < nq) v = qstar[i];
    else if (i - nq < nfeat) v = outb[i - nq];
    dst[i] = v;
}

extern "C" void kernel_launch(void* const* d_in, const int* in_sizes, int n_in,
                              void* d_out, int out_size, void* d_ws, size_t ws_size,
                              hipStream_t stream) {
    constexpr int N = GN, E = GE, B = GB;

    char* ws = (char*)d_ws;
    size_t off = 0;
    auto alloc = [&](size_t bytes) { size_t o = off; off = (off + bytes + 255) & ~(size_t)255; return o; };

    int*   fl     = (int*)  (ws + alloc(19 * 4));
    int*   flagE  = (int*)  (ws + alloc(256));
    int*   flagG  = (int*)  (ws + alloc(256));
    float* counts = (float*)(ws + alloc((size_t)N * 4));
    int*   rowptr = (int*)  (ws + alloc((size_t)(B + 1) * 4));
    float* outbuf = (float*)(ws + alloc((size_t)N * 64 * 4));
    float* agg    = (float*)(ws + alloc((size_t)N * 64 * 4));
    float* qstar  = (float*)(ws + alloc((size_t)B * 128 * 4));   // qstar+hs+cs contiguous
    float* hsb    = (float*)(ws + alloc((size_t)B * 64 * 4));
    float* csb    = (float*)(ws + alloc((size_t)B * 64 * 4));
    __hip_bfloat16* h1  = (__hip_bfloat16*)(ws + alloc((size_t)E * 128 * 2));
    __hip_bfloat16* w2T = (__hip_bfloat16*)(ws + alloc((size_t)4096 * 128 * 2));
    float* wpk    = (float*)(ws + alloc((size_t)64 * 384 * 4));

    const int fidx[15]  = {4, 5, 6, 7, 8, 9, 10, 11, 12, 13, 14, 15, 16, 17, 18};
    const int fsize[15] = {75 * 64, 64, 16 * 128, 128, 128 * 4096, 4096, 64,
                           192 * 64, 192 * 64, 192, 192, 256 * 128, 256 * 64, 256, 256};
    float* F[19] = {};
    for (int t = 0; t < 15; ++t) F[fidx[t]] = (float*)(ws + alloc((size_t)fsize[t] * 4));

    // batched dtype detection
    DetectArgs da;
    da.src[0] = d_in[0]; da.nhalf[0] = N * 75; da.fi[0] = 0;
    da.src[1] = d_in[1]; da.nhalf[1] = E * 16; da.fi[1] = 1;
    for (int t = 0; t < 15; ++t) { da.src[2 + t] = d_in[fidx[t]]; da.nhalf[2 + t] = fsize[t]; da.fi[2 + t] = fidx[t]; }
    k_dtype_all<<<17, 256, 0, stream>>>(da, fl);
    k_i64<<<1, 256, 0, stream>>>((const unsigned int*)d_in[2], (long long)2 * E, flagE);
    k_i64<<<1, 256, 0, stream>>>((const unsigned int*)d_in[3], (long long)N, flagG);

    // batched f32 conversion + w2 transpose + GRU weight repack
    CvtArgs ca;
    int pre = 0;
    for (int t = 0; t < 15; ++t) {
        ca.src[t] = d_in[fidx[t]]; ca.dst[t] = F[fidx[t]]; ca.n[t] = fsize[t]; ca.fi[t] = fidx[t];
        ca.pre[t] = pre; pre += (fsize[t] + 255) / 256;
    }
    ca.pre[15] = pre;
    k_cvt_all<<<pre, 256, 0, stream>>>(ca, fl);
    k_t2<<<4096 * 16 / 256, 256, 0, stream>>>(d_in[8], w2T, fl + 8);
    k_gpack<<<(64 * 384 + 255) / 256, 256, 0, stream>>>(F[11], F[12], wpk);

    hipMemsetAsync(counts, 0, (size_t)N * 4, stream);
    hipMemsetAsync(qstar, 0, (size_t)(B * 128 + B * 64 + B * 64) * 4, stream);

    k_counts<<<E / 256, 256, 0, stream>>>(d_in[2], flagE, counts, E);
    k_rowptr<<<(B + 1 + 255) / 256, 256, 0, stream>>>(d_in[3], flagG, rowptr, N, B);
    k_lin0<<<N / 4, 256, 0, stream>>>(d_in[0], F[4], F[5], outbuf, fl + 0);
    k1_h1<<<E / 2, 256, 0, stream>>>(d_in[1], F[6], F[7], h1, fl + 1);

    for (int it = 0; it < 3; ++it) {
        hipMemsetAsync(agg, 0, (size_t)N * 64 * 4, stream);
        k23_fused<<<E / 64, 256, 0, stream>>>(h1, w2T, F[9], outbuf, d_in[2], flagE, agg);
        k4_gru<<<N / 256, 256, 0, stream>>>(agg, counts, F[10], wpk, F[13], F[14], outbuf);
    }
    for (int t = 0; t < 3; ++t) {
        k5_lstm<<<B, 256, 0, stream>>>(qstar, hsb, csb, F[15], F[16], F[17], F[18]);
        k5_attn<<<B, 64, 0, stream>>>(outbuf, hsb, rowptr, qstar);
    }
    k_out<<<(out_size + 255) / 256, 256, 0, stream>>>(qstar, outbuf, (float*)d_out,
                                                      B * 128, N * 64, out_size);
}

// Round 10
// 1689.844 us; speedup vs baseline: 7.4514x; 1.1821x over previous
//
#include <hip/hip_runtime.h>
#include <hip/hip_bf16.h>

#define GN 65536
#define GE 131072
#define GB 2048

typedef __attribute__((ext_vector_type(8))) short short8;
typedef __attribute__((ext_vector_type(4))) float floatx4;

static __device__ __forceinline__ float sigm(float x) { return 1.0f / (1.0f + __expf(-x)); }
static __device__ __forceinline__ float bf2f(unsigned short u) {
    union { unsigned int i; float f; } v; v.i = ((unsigned int)u) << 16; return v.f;
}
static __device__ __forceinline__ int geti(const void* p, long long i, int f64) {
    return f64 ? (int)((const long long*)p)[i] : ((const int*)p)[i];
}

// ---- batched per-tensor float dtype detector (one block per tensor) ----
struct DetectArgs { const void* src[17]; int nhalf[17]; int fi[17]; };
__global__ void k_dtype_all(DetectArgs a, int* __restrict__ flags) {
    const unsigned short* p = (const unsigned short*)a.src[blockIdx.x];
    const int n0 = a.nhalf[blockIdx.x];
    const int n = n0 < 16384 ? n0 : 16384;
    __shared__ unsigned int sAny[256], sOr[256];
    unsigned int any = 0, orEven = 0;
    for (int i = threadIdx.x; i < n; i += 256) {
        const unsigned short u = p[i];
        const float av = fabsf(bf2f(u));
        if (!(av <= 1e6f)) any = 1u;
        if ((i & 1) == 0) orEven |= u;
    }
    sAny[threadIdx.x] = any; sOr[threadIdx.x] = orEven;
    __syncthreads();
    for (int s = 128; s > 0; s >>= 1) {
        if (threadIdx.x < s) {
            sAny[threadIdx.x] |= sAny[threadIdx.x + s];
            sOr[threadIdx.x]  |= sOr[threadIdx.x + s];
        }
        __syncthreads();
    }
    if (threadIdx.x == 0) flags[a.fi[blockIdx.x]] = (sAny[0] || sOr[0] == 0u) ? 1 : 0;
}

// int64 detector, sampled
__global__ void k_i64(const unsigned int* __restrict__ p, long long nwords, int* __restrict__ flag) {
    const long long lim = nwords < 16384 ? nwords : 16384;
    __shared__ unsigned int s[256];
    unsigned int acc = 0;
    for (long long w = 1 + 2 * (long long)threadIdx.x; w < lim; w += 512) acc |= p[w];
    s[threadIdx.x] = acc;
    __syncthreads();
    for (int st = 128; st > 0; st >>= 1) {
        if (threadIdx.x < st) s[threadIdx.x] |= s[threadIdx.x + st];
        __syncthreads();
    }
    if (threadIdx.x == 0) *flag = (s[0] == 0u) ? 1 : 0;
}

// ---- batched f32 canonicalization of the 15 small float tensors ----
struct CvtArgs { const void* src[15]; float* dst[15]; int n[15]; int fi[15]; int pre[16]; };
__global__ void k_cvt_all(CvtArgs a, const int* __restrict__ flags) {
    const int b = blockIdx.x;
    int t = 0;
    while (t < 14 && b >= a.pre[t + 1]) ++t;
    const int i = (b - a.pre[t]) * 256 + threadIdx.x;
    if (i >= a.n[t]) return;
    const int f = flags[a.fi[t]];
    a.dst[t][i] = f ? ((const float*)a.src[t])[i] : bf2f(((const unsigned short*)a.src[t])[i]);
}

// transpose w2 [128][4096] -> w2T bf16 [4096][128]
__global__ __launch_bounds__(256) void k_t2(const void* __restrict__ src,
                                            __hip_bfloat16* __restrict__ w2T,
                                            const int* __restrict__ flag) {
    const int idx = blockIdx.x * 256 + threadIdx.x;
    const int kb8 = idx >> 12;
    const int n = idx & 4095;
    const int isf32 = *flag;
    short8 v;
    #pragma unroll
    for (int j = 0; j < 8; ++j) {
        const size_t si = (size_t)(kb8 * 8 + j) * 4096 + n;
        const float f = isf32 ? ((const float*)src)[si] : bf2f(((const unsigned short*)src)[si]);
        const __hip_bfloat16 b = __float2bfloat16(f);
        v[j] = *(const short*)&b;
    }
    *(short8*)(w2T + (size_t)n * 128 + kb8 * 8) = v;
}

// repack GRU weights: wpk[d][6][64] (wi_r,wi_z,wi_n,wh_r,wh_z,wh_n per d)
__global__ void k_gpack(const float* __restrict__ w_ih, const float* __restrict__ w_hh,
                        float* __restrict__ wpk) {
    int idx = blockIdx.x * 256 + threadIdx.x;
    if (idx >= 64 * 384) return;
    const int d = idx / 384, rem = idx % 384, g = rem >> 6, k = rem & 63;
    wpk[idx] = (g < 3) ? w_ih[(g * 64 + d) * 64 + k] : w_hh[((g - 3) * 64 + d) * 64 + k];
}

__global__ void k_counts(const void* __restrict__ eidx, const int* __restrict__ fi64,
                         float* __restrict__ counts, int E_) {
    int e = blockIdx.x * 256 + threadIdx.x;
    if (e < E_) atomicAdd(&counts[geti(eidx, (long long)E_ + e, *fi64)], 1.0f);
}

__global__ void k_rowptr(const void* __restrict__ gi, const int* __restrict__ fi64,
                         int* __restrict__ rowptr, int N_, int B_) {
    int g = blockIdx.x * 256 + threadIdx.x;
    if (g > B_) return;
    const int f64 = *fi64;
    int lo = 0, hi = N_;
    while (lo < hi) { int mid = (lo + hi) >> 1; if (geti(gi, mid, f64) < g) lo = mid + 1; else hi = mid; }
    rowptr[g] = lo;
}

// lin0: out = relu(nf @ lin0_w + b)
__global__ __launch_bounds__(256) void k_lin0(const void* __restrict__ nf_raw,
                                              const float* __restrict__ w,
                                              const float* __restrict__ b,
                                              float* __restrict__ out,
                                              const int* __restrict__ flag) {
    const int ln = threadIdx.x >> 6;
    const int d = threadIdx.x & 63;
    const int n = blockIdx.x * 4 + ln;
    const int isf32 = *flag;
    __shared__ float s_nf[4][76];
    const size_t base = (size_t)n * 75;
    s_nf[ln][d] = isf32 ? ((const float*)nf_raw)[base + d] : bf2f(((const unsigned short*)nf_raw)[base + d]);
    if (d < 11) s_nf[ln][64 + d] = isf32 ? ((const float*)nf_raw)[base + 64 + d]
                                         : bf2f(((const unsigned short*)nf_raw)[base + 64 + d]);
    __syncthreads();
    float acc = b[d];
    #pragma unroll
    for (int i = 0; i < 75; ++i) acc += s_nf[ln][i] * w[i * 64 + d];
    out[(size_t)n * 64 + d] = fmaxf(acc, 0.0f);
}

// h1 = relu(ef @ w1 + b1) -> bf16
__global__ __launch_bounds__(256) void k1_h1(const void* __restrict__ ef_raw,
                                             const float* __restrict__ w1,
                                             const float* __restrict__ b1,
                                             __hip_bfloat16* __restrict__ h1,
                                             const int* __restrict__ flag) {
    const int le = threadIdx.x >> 7;
    const int j = threadIdx.x & 127;
    const int e = blockIdx.x * 2 + le;
    const int isf32 = *flag;
    __shared__ float efs[2][16];
    if (j < 16) {
        const size_t idx = (size_t)e * 16 + j;
        efs[le][j] = isf32 ? ((const float*)ef_raw)[idx] : bf2f(((const unsigned short*)ef_raw)[idx]);
    }
    __syncthreads();
    float acc = b1[j];
    #pragma unroll
    for (int i = 0; i < 16; ++i) acc += efs[le][i] * w1[i * 128 + j];
    h1[(size_t)e * 128 + j] = __float2bfloat16(fmaxf(acc, 0.0f));
}

// FUSED NNConv (r9-verified): per 64-edge block compute W on the fly and
// reduce msg in registers; atomic scatter to agg[dst].
__global__ __launch_bounds__(256) void k23_fused(const __hip_bfloat16* __restrict__ h1,
                                                 const __hip_bfloat16* __restrict__ w2T,
                                                 const float* __restrict__ b2,
                                                 const float* __restrict__ out,
                                                 const void* __restrict__ eidx,
                                                 const int* __restrict__ fi64,
                                                 float* __restrict__ agg) {
    __shared__ __hip_bfloat16 As[64][136];
    __shared__ __hip_bfloat16 Bs[128][72];
    __shared__ float ylds[64][68];
    __shared__ int sidx[128];
    const int tid = threadIdx.x;
    const int e0 = blockIdx.x * 64;

    if (tid < 64) sidx[tid] = geti(eidx, e0 + tid, *fi64);
    else if (tid < 128) sidx[tid] = geti(eidx, (long long)GE + e0 + (tid - 64), *fi64);
    #pragma unroll
    for (int i = 0; i < 4; ++i) {
        int chunk = i * 256 + tid;
        int r = chunk >> 4, c = (chunk & 15) * 8;
        *(int4*)(&As[r][c]) = *(const int4*)(h1 + (size_t)(e0 + r) * 128 + c);
    }
    __syncthreads();
    {
        const int e = tid >> 2, d0 = (tid & 3) * 16;
        const float* srow = out + (size_t)sidx[e] * 64 + d0;
        #pragma unroll
        for (int j = 0; j < 4; ++j)
            *(float4*)(&ylds[e][d0 + j * 4]) = *(const float4*)(srow + j * 4);
    }

    const int wave = tid >> 6, lane = tid & 63;
    const int wm = (wave >> 1) * 32;
    const int wn = (wave & 1) * 64;
    const int lr = lane & 15, quad = lane >> 4;
    float msum[2][4][4] = {};

    for (int n0 = 0; n0 < 4096; n0 += 128) {
        floatx4 acc[2][4] = {};
        const int dcur = (n0 + wn) >> 6;
        #pragma unroll
        for (int kst = 0; kst < 2; ++kst) {
            const int kb = kst * 64;
            #pragma unroll
            for (int i = 0; i < 4; ++i) {
                int chunk = i * 256 + tid;
                int r = chunk >> 3, c = (chunk & 7) * 8;
                *(int4*)(&Bs[r][c]) = *(const int4*)(w2T + (size_t)(n0 + r) * 128 + kb + c);
            }
            __syncthreads();
            #pragma unroll
            for (int ks = 0; ks < 64; ks += 32) {
                short8 af[2], bfr[4];
                #pragma unroll
                for (int mt = 0; mt < 2; ++mt)
                    af[mt] = *(const short8*)(&As[wm + mt * 16 + lr][kb + ks + quad * 8]);
                #pragma unroll
                for (int nt = 0; nt < 4; ++nt)
                    bfr[nt] = *(const short8*)(&Bs[wn + nt * 16 + lr][ks + quad * 8]);
                #pragma unroll
                for (int mt = 0; mt < 2; ++mt)
                    #pragma unroll
                    for (int nt = 0; nt < 4; ++nt)
                        acc[mt][nt] = __builtin_amdgcn_mfma_f32_16x16x32_bf16(af[mt], bfr[nt], acc[mt][nt], 0, 0, 0);
            }
            __syncthreads();
        }
        #pragma unroll
        for (int nt = 0; nt < 4; ++nt) {
            const float b2v = b2[n0 + wn + nt * 16 + lr];
            #pragma unroll
            for (int mt = 0; mt < 2; ++mt) {
                #pragma unroll
                for (int r = 0; r < 4; ++r) {
                    const int row = wm + mt * 16 + quad * 4 + r;
                    msum[mt][nt][r] = fmaf(ylds[row][dcur], acc[mt][nt][r] + b2v, msum[mt][nt][r]);
                }
            }
        }
    }
    #pragma unroll
    for (int mt = 0; mt < 2; ++mt)
        #pragma unroll
        for (int r = 0; r < 4; ++r) {
            const int row = wm + mt * 16 + quad * 4 + r;
            const int dn = sidx[64 + row];
            #pragma unroll
            for (int nt = 0; nt < 4; ++nt)
                atomicAdd(&agg[(size_t)dn * 64 + nt * 16 + lr], msum[mt][nt][r]);
        }
}

// GRU v3: block = 64 nodes; the 4 waves split the d-loop (16 d's each) over
// the SAME 64 nodes -> grid 1024 blocks, ~12 waves/CU (vs r9's 1 wave/SIMD).
// Weight reads stay wave-uniform (scalar); each wave streams only 24KB of wpk.
__global__ __launch_bounds__(256) void k4_gru(const float* __restrict__ agg,
                                              const float* __restrict__ counts,
                                              const float* __restrict__ cbias,
                                              const float* __restrict__ wpk,
                                              const float* __restrict__ b_ih,
                                              const float* __restrict__ b_hh,
                                              float* __restrict__ out) {
    const int wv = threadIdx.x >> 6;
    const int lane = threadIdx.x & 63;
    const int nb0 = blockIdx.x * 64;
    __shared__ float sM[64][65], sH[64][65];

    // stage agg & h: each wave loads 16 rows, coalesced
    #pragma unroll 4
    for (int i = 0; i < 16; ++i) {
        const int r = i * 4 + wv;
        sM[r][lane] = agg[(size_t)(nb0 + r) * 64 + lane];
        sH[r][lane] = out[(size_t)(nb0 + r) * 64 + lane];
    }
    __syncthreads();
    const float rcnt = 1.0f / fmaxf(counts[nb0 + lane], 1.0f);
    float m[64], h[64];
    #pragma unroll
    for (int k = 0; k < 64; ++k) {
        m[k] = fmaxf(sM[lane][k] * rcnt + cbias[k], 0.0f);
        h[k] = sH[lane][k];
    }
    __syncthreads();   // all reg loads done before sM is overwritten

    const int d0 = wv * 16;
    #pragma unroll 1
    for (int dd = 0; dd < 16; ++dd) {
        const int d = d0 + dd;
        const float* wr = wpk + d * 384;
        float a0 = b_ih[d], a1 = b_ih[64 + d], a2 = b_ih[128 + d];
        float g0 = b_hh[d], g1 = b_hh[64 + d], g2 = b_hh[128 + d];
        #pragma unroll
        for (int k = 0; k < 64; ++k) {
            a0 = fmaf(m[k], wr[k], a0);
            a1 = fmaf(m[k], wr[64 + k], a1);
            a2 = fmaf(m[k], wr[128 + k], a2);
            g0 = fmaf(h[k], wr[192 + k], g0);
            g1 = fmaf(h[k], wr[256 + k], g1);
            g2 = fmaf(h[k], wr[320 + k], g2);
        }
        const float r_ = sigm(a0 + g0);
        const float z  = sigm(a1 + g1);
        const float nn = tanhf(a2 + r_ * g2);
        const float hd = sH[lane][d];          // old h[d] via LDS (runtime d)
        sM[lane][d] = (1.0f - z) * nn + z * hd;  // h_new staged in sM
    }
    __syncthreads();
    // coalesced writeback
    #pragma unroll 4
    for (int i = 0; i < 16; ++i) {
        const int r = i * 4 + wv;
        out[(size_t)(nb0 + r) * 64 + lane] = sM[r][lane];
    }
}

__global__ __launch_bounds__(256) void k5_lstm(float* __restrict__ qstar,
                                               float* __restrict__ hs, float* __restrict__ cs,
                                               const float* __restrict__ w_ih,
                                               const float* __restrict__ w_hh,
                                               const float* __restrict__ b_ih,
                                               const float* __restrict__ b_hh) {
    const int g = blockIdx.x;
    const int j = threadIdx.x;
    __shared__ float qs[128], hv[64], gates[256];
    if (j < 128) qs[j] = qstar[(size_t)g * 128 + j];
    else if (j < 192) hv[j - 128] = hs[(size_t)g * 64 + (j - 128)];
    __syncthreads();
    float acc = b_ih[j] + b_hh[j];
    for (int k4 = 0; k4 < 128; k4 += 4) {
        float4 v = *(const float4*)(w_ih + (size_t)j * 128 + k4);
        const float* pv = (const float*)&v;
        #pragma unroll
        for (int t = 0; t < 4; ++t) acc += qs[k4 + t] * pv[t];
    }
    for (int k4 = 0; k4 < 64; k4 += 4) {
        float4 v = *(const float4*)(w_hh + (size_t)j * 64 + k4);
        const float* pv = (const float*)&v;
        #pragma unroll
        for (int t = 0; t < 4; ++t) acc += hv[k4 + t] * pv[t];
    }
    gates[j] = acc;
    __syncthreads();
    if (j < 64) {
        const float ig = sigm(gates[j]);
        const float fg = sigm(gates[64 + j]);
        const float gg = tanhf(gates[128 + j]);
        const float og = sigm(gates[192 + j]);
        const float c = fg * cs[(size_t)g * 64 + j] + ig * gg;
        const float h = og * tanhf(c);
        cs[(size_t)g * 64 + j] = c;
        hs[(size_t)g * 64 + j] = h;
        qstar[(size_t)g * 128 + j] = h;
    }
}

// Set2Set attention: single-pass online softmax, wave per graph
__global__ __launch_bounds__(64) void k5_attn(const float* __restrict__ out,
                                              const float* __restrict__ hs,
                                              const int* __restrict__ rowptr,
                                              float* __restrict__ qstar) {
    const int g = blockIdx.x;
    const int lane = threadIdx.x;
    const float q = hs[(size_t)g * 64 + lane];
    const int start = rowptr[g], end = rowptr[g + 1];
    float m = -3.4e38f, S = 0.0f, racc = 0.0f;
    for (int n = start; n < end; ++n) {
        const float ov = out[(size_t)n * 64 + lane];
        float p = ov * q;
        #pragma unroll
        for (int off = 1; off < 64; off <<= 1) p += __shfl_xor(p, off);
        if (p > m) {
            const float sc = __expf(m - p);
            S = S * sc + 1.0f;
            racc = racc * sc + ov;
            m = p;
        } else {
            const float w = __expf(p - m);
            S += w;
            racc += w * ov;
        }
    }
    qstar[(size_t)g * 128 + 64 + lane] = racc / (S + 1e-16f);
}

__global__ void k_out(const float* __restrict__ qstar, const float* __restrict__ outb,
                      float* __restrict__ dst, int nq, int nfeat, int out_n) {
    int i = blockIdx.x * 256 + threadIdx.x;
    if (i >= out_n) return;
    float v = 0.0f;
    if (i < nq) v = qstar[i];
    else if (i - nq < nfeat) v = outb[i - nq];
    dst[i] = v;
}

extern "C" void kernel_launch(void* const* d_in, const int* in_sizes, int n_in,
                              void* d_out, int out_size, void* d_ws, size_t ws_size,
                              hipStream_t stream) {
    constexpr int N = GN, E = GE, B = GB;

    char* ws = (char*)d_ws;
    size_t off = 0;
    auto alloc = [&](size_t bytes) { size_t o = off; off = (off + bytes + 255) & ~(size_t)255; return o; };

    int*   fl     = (int*)  (ws + alloc(19 * 4));
    int*   flagE  = (int*)  (ws + alloc(256));
    int*   flagG  = (int*)  (ws + alloc(256));
    float* counts = (float*)(ws + alloc((size_t)N * 4));
    int*   rowptr = (int*)  (ws + alloc((size_t)(B + 1) * 4));
    float* outbuf = (float*)(ws + alloc((size_t)N * 64 * 4));
    float* agg    = (float*)(ws + alloc((size_t)N * 64 * 4));
    float* qstar  = (float*)(ws + alloc((size_t)B * 128 * 4));
    float* hsb    = (float*)(ws + alloc((size_t)B * 64 * 4));
    float* csb    = (float*)(ws + alloc((size_t)B * 64 * 4));
    __hip_bfloat16* h1  = (__hip_bfloat16*)(ws + alloc((size_t)E * 128 * 2));
    __hip_bfloat16* w2T = (__hip_bfloat16*)(ws + alloc((size_t)4096 * 128 * 2));
    float* wpk    = (float*)(ws + alloc((size_t)64 * 384 * 4));

    const int fidx[15]  = {4, 5, 6, 7, 8, 9, 10, 11, 12, 13, 14, 15, 16, 17, 18};
    const int fsize[15] = {75 * 64, 64, 16 * 128, 128, 128 * 4096, 4096, 64,
                           192 * 64, 192 * 64, 192, 192, 256 * 128, 256 * 64, 256, 256};
    float* F[19] = {};
    for (int t = 0; t < 15; ++t) F[fidx[t]] = (float*)(ws + alloc((size_t)fsize[t] * 4));

    DetectArgs da;
    da.src[0] = d_in[0]; da.nhalf[0] = N * 75; da.fi[0] = 0;
    da.src[1] = d_in[1]; da.nhalf[1] = E * 16; da.fi[1] = 1;
    for (int t = 0; t < 15; ++t) { da.src[2 + t] = d_in[fidx[t]]; da.nhalf[2 + t] = fsize[t]; da.fi[2 + t] = fidx[t]; }
    k_dtype_all<<<17, 256, 0, stream>>>(da, fl);
    k_i64<<<1, 256, 0, stream>>>((const unsigned int*)d_in[2], (long long)2 * E, flagE);
    k_i64<<<1, 256, 0, stream>>>((const unsigned int*)d_in[3], (long long)N, flagG);

    CvtArgs ca;
    int pre = 0;
    for (int t = 0; t < 15; ++t) {
        ca.src[t] = d_in[fidx[t]]; ca.dst[t] = F[fidx[t]]; ca.n[t] = fsize[t]; ca.fi[t] = fidx[t];
        ca.pre[t] = pre; pre += (fsize[t] + 255) / 256;
    }
    ca.pre[15] = pre;
    k_cvt_all<<<pre, 256, 0, stream>>>(ca, fl);
    k_t2<<<4096 * 16 / 256, 256, 0, stream>>>(d_in[8], w2T, fl + 8);
    k_gpack<<<(64 * 384 + 255) / 256, 256, 0, stream>>>(F[11], F[12], wpk);

    hipMemsetAsync(counts, 0, (size_t)N * 4, stream);
    hipMemsetAsync(qstar, 0, (size_t)(B * 128 + B * 64 + B * 64) * 4, stream);

    k_counts<<<E / 256, 256, 0, stream>>>(d_in[2], flagE, counts, E);
    k_rowptr<<<(B + 1 + 255) / 256, 256, 0, stream>>>(d_in[3], flagG, rowptr, N, B);
    k_lin0<<<N / 4, 256, 0, stream>>>(d_in[0], F[4], F[5], outbuf, fl + 0);
    k1_h1<<<E / 2, 256, 0, stream>>>(d_in[1], F[6], F[7], h1, fl + 1);

    for (int it = 0; it < 3; ++it) {
        hipMemsetAsync(agg, 0, (size_t)N * 64 * 4, stream);
        k23_fused<<<E / 64, 256, 0, stream>>>(h1, w2T, F[9], outbuf, d_in[2], flagE, agg);
        k4_gru<<<N / 64, 256, 0, stream>>>(agg, counts, F[10], wpk, F[13], F[14], outbuf);
    }
    for (int t = 0; t < 3; ++t) {
        k5_lstm<<<B, 256, 0, stream>>>(qstar, hsb, csb, F[15], F[16], F[17], F[18]);
        k5_attn<<<B, 64, 0, stream>>>(outbuf, hsb, rowptr, qstar);
    }
    k_out<<<(out_size + 255) / 256, 256, 0, stream>>>(qstar, outbuf, (float*)d_out,
                                                      B * 128, N * 64, out_size);
}

// Round 11
// 1624.814 us; speedup vs baseline: 7.7496x; 1.0400x over previous
//
#include <hip/hip_runtime.h>
#include <hip/hip_bf16.h>

#define GN 65536
#define GE 131072
#define GB 2048

typedef __attribute__((ext_vector_type(8))) short short8;
typedef __attribute__((ext_vector_type(4))) float floatx4;

static __device__ __forceinline__ float sigm(float x) { return 1.0f / (1.0f + __expf(-x)); }
static __device__ __forceinline__ float bf2f(unsigned short u) {
    union { unsigned int i; float f; } v; v.i = ((unsigned int)u) << 16; return v.f;
}
static __device__ __forceinline__ int geti(const void* p, long long i, int f64) {
    return f64 ? (int)((const long long*)p)[i] : ((const int*)p)[i];
}

// ---- batched per-tensor float dtype detector (one block per tensor) ----
struct DetectArgs { const void* src[17]; int nhalf[17]; int fi[17]; };
__global__ void k_dtype_all(DetectArgs a, int* __restrict__ flags) {
    const unsigned short* p = (const unsigned short*)a.src[blockIdx.x];
    const int n0 = a.nhalf[blockIdx.x];
    const int n = n0 < 16384 ? n0 : 16384;
    __shared__ unsigned int sAny[256], sOr[256];
    unsigned int any = 0, orEven = 0;
    for (int i = threadIdx.x; i < n; i += 256) {
        const unsigned short u = p[i];
        const float av = fabsf(bf2f(u));
        if (!(av <= 1e6f)) any = 1u;
        if ((i & 1) == 0) orEven |= u;
    }
    sAny[threadIdx.x] = any; sOr[threadIdx.x] = orEven;
    __syncthreads();
    for (int s = 128; s > 0; s >>= 1) {
        if (threadIdx.x < s) {
            sAny[threadIdx.x] |= sAny[threadIdx.x + s];
            sOr[threadIdx.x]  |= sOr[threadIdx.x + s];
        }
        __syncthreads();
    }
    if (threadIdx.x == 0) flags[a.fi[blockIdx.x]] = (sAny[0] || sOr[0] == 0u) ? 1 : 0;
}

// int64 detector, sampled
__global__ void k_i64(const unsigned int* __restrict__ p, long long nwords, int* __restrict__ flag) {
    const long long lim = nwords < 16384 ? nwords : 16384;
    __shared__ unsigned int s[256];
    unsigned int acc = 0;
    for (long long w = 1 + 2 * (long long)threadIdx.x; w < lim; w += 512) acc |= p[w];
    s[threadIdx.x] = acc;
    __syncthreads();
    for (int st = 128; st > 0; st >>= 1) {
        if (threadIdx.x < st) s[threadIdx.x] |= s[threadIdx.x + st];
        __syncthreads();
    }
    if (threadIdx.x == 0) *flag = (s[0] == 0u) ? 1 : 0;
}

// ---- batched f32 canonicalization of the 15 small float tensors ----
struct CvtArgs { const void* src[15]; float* dst[15]; int n[15]; int fi[15]; int pre[16]; };
__global__ void k_cvt_all(CvtArgs a, const int* __restrict__ flags) {
    const int b = blockIdx.x;
    int t = 0;
    while (t < 14 && b >= a.pre[t + 1]) ++t;
    const int i = (b - a.pre[t]) * 256 + threadIdx.x;
    if (i >= a.n[t]) return;
    const int f = flags[a.fi[t]];
    a.dst[t][i] = f ? ((const float*)a.src[t])[i] : bf2f(((const unsigned short*)a.src[t])[i]);
}

// transpose w2 [128][4096] -> w2T bf16 [4096][128]
__global__ __launch_bounds__(256) void k_t2(const void* __restrict__ src,
                                            __hip_bfloat16* __restrict__ w2T,
                                            const int* __restrict__ flag) {
    const int idx = blockIdx.x * 256 + threadIdx.x;
    const int kb8 = idx >> 12;
    const int n = idx & 4095;
    const int isf32 = *flag;
    short8 v;
    #pragma unroll
    for (int j = 0; j < 8; ++j) {
        const size_t si = (size_t)(kb8 * 8 + j) * 4096 + n;
        const float f = isf32 ? ((const float*)src)[si] : bf2f(((const unsigned short*)src)[si]);
        const __hip_bfloat16 b = __float2bfloat16(f);
        v[j] = *(const short*)&b;
    }
    *(short8*)(w2T + (size_t)n * 128 + kb8 * 8) = v;
}

// repack GRU weights: wpk[d][6][64]
__global__ void k_gpack(const float* __restrict__ w_ih, const float* __restrict__ w_hh,
                        float* __restrict__ wpk) {
    int idx = blockIdx.x * 256 + threadIdx.x;
    if (idx >= 64 * 384) return;
    const int d = idx / 384, rem = idx % 384, g = rem >> 6, k = rem & 63;
    wpk[idx] = (g < 3) ? w_ih[(g * 64 + d) * 64 + k] : w_hh[((g - 3) * 64 + d) * 64 + k];
}

__global__ void k_counts(const void* __restrict__ eidx, const int* __restrict__ fi64,
                         float* __restrict__ counts, int E_) {
    int e = blockIdx.x * 256 + threadIdx.x;
    if (e < E_) atomicAdd(&counts[geti(eidx, (long long)E_ + e, *fi64)], 1.0f);
}

__global__ void k_rowptr(const void* __restrict__ gi, const int* __restrict__ fi64,
                         int* __restrict__ rowptr, int N_, int B_) {
    int g = blockIdx.x * 256 + threadIdx.x;
    if (g > B_) return;
    const int f64 = *fi64;
    int lo = 0, hi = N_;
    while (lo < hi) { int mid = (lo + hi) >> 1; if (geti(gi, mid, f64) < g) lo = mid + 1; else hi = mid; }
    rowptr[g] = lo;
}

// lin0: out = relu(nf @ lin0_w + b)
__global__ __launch_bounds__(256) void k_lin0(const void* __restrict__ nf_raw,
                                              const float* __restrict__ w,
                                              const float* __restrict__ b,
                                              float* __restrict__ out,
                                              const int* __restrict__ flag) {
    const int ln = threadIdx.x >> 6;
    const int d = threadIdx.x & 63;
    const int n = blockIdx.x * 4 + ln;
    const int isf32 = *flag;
    __shared__ float s_nf[4][76];
    const size_t base = (size_t)n * 75;
    s_nf[ln][d] = isf32 ? ((const float*)nf_raw)[base + d] : bf2f(((const unsigned short*)nf_raw)[base + d]);
    if (d < 11) s_nf[ln][64 + d] = isf32 ? ((const float*)nf_raw)[base + 64 + d]
                                         : bf2f(((const unsigned short*)nf_raw)[base + 64 + d]);
    __syncthreads();
    float acc = b[d];
    #pragma unroll
    for (int i = 0; i < 75; ++i) acc += s_nf[ln][i] * w[i * 64 + d];
    out[(size_t)n * 64 + d] = fmaxf(acc, 0.0f);
}

// h1 = relu(ef @ w1 + b1) -> bf16
__global__ __launch_bounds__(256) void k1_h1(const void* __restrict__ ef_raw,
                                             const float* __restrict__ w1,
                                             const float* __restrict__ b1,
                                             __hip_bfloat16* __restrict__ h1,
                                             const int* __restrict__ flag) {
    const int le = threadIdx.x >> 7;
    const int j = threadIdx.x & 127;
    const int e = blockIdx.x * 2 + le;
    const int isf32 = *flag;
    __shared__ float efs[2][16];
    if (j < 16) {
        const size_t idx = (size_t)e * 16 + j;
        efs[le][j] = isf32 ? ((const float*)ef_raw)[idx] : bf2f(((const unsigned short*)ef_raw)[idx]);
    }
    __syncthreads();
    float acc = b1[j];
    #pragma unroll
    for (int i = 0; i < 16; ++i) acc += efs[le][i] * w1[i * 128 + j];
    h1[(size_t)e * 128 + j] = __float2bfloat16(fmaxf(acc, 0.0f));
}

// FUSED NNConv v3: full-K Bs staging (2 barriers/tile, 32 MFMA/wave between)
// + A-fragments hoisted to registers (As LDS read once, before the n0 loop).
__global__ __launch_bounds__(256) void k23_fused(const __hip_bfloat16* __restrict__ h1,
                                                 const __hip_bfloat16* __restrict__ w2T,
                                                 const float* __restrict__ b2,
                                                 const float* __restrict__ out,
                                                 const void* __restrict__ eidx,
                                                 const int* __restrict__ fi64,
                                                 float* __restrict__ agg) {
    __shared__ __hip_bfloat16 As[64][136];
    __shared__ __hip_bfloat16 Bs[128][136];
    __shared__ float ylds[64][68];
    __shared__ int sidx[128];
    const int tid = threadIdx.x;
    const int e0 = blockIdx.x * 64;

    if (tid < 64) sidx[tid] = geti(eidx, e0 + tid, *fi64);
    else if (tid < 128) sidx[tid] = geti(eidx, (long long)GE + e0 + (tid - 64), *fi64);
    #pragma unroll
    for (int i = 0; i < 4; ++i) {
        int chunk = i * 256 + tid;
        int r = chunk >> 4, c = (chunk & 15) * 8;
        *(int4*)(&As[r][c]) = *(const int4*)(h1 + (size_t)(e0 + r) * 128 + c);
    }
    __syncthreads();
    {
        const int e = tid >> 2, d0 = (tid & 3) * 16;
        const float* srow = out + (size_t)sidx[e] * 64 + d0;
        #pragma unroll
        for (int j = 0; j < 4; ++j)
            *(float4*)(&ylds[e][d0 + j * 4]) = *(const float4*)(srow + j * 4);
    }

    const int wave = tid >> 6, lane = tid & 63;
    const int wm = (wave >> 1) * 32;
    const int wn = (wave & 1) * 64;
    const int lr = lane & 15, quad = lane >> 4;

    // hoist all A fragments for full K=128 into registers (32 VGPRs)
    short8 af[2][4];
    #pragma unroll
    for (int mt = 0; mt < 2; ++mt)
        #pragma unroll
        for (int kk = 0; kk < 4; ++kk)
            af[mt][kk] = *(const short8*)(&As[wm + mt * 16 + lr][kk * 32 + quad * 8]);

    float msum[2][4][4] = {};

    for (int n0 = 0; n0 < 4096; n0 += 128) {
        floatx4 acc[2][4] = {};
        const int dcur = (n0 + wn) >> 6;
        #pragma unroll
        for (int i = 0; i < 8; ++i) {        // Bs: 128 rows x full K=128
            int chunk = i * 256 + tid;
            int r = chunk >> 4, c = (chunk & 15) * 8;
            *(int4*)(&Bs[r][c]) = *(const int4*)(w2T + (size_t)(n0 + r) * 128 + c);
        }
        __syncthreads();
        #pragma unroll
        for (int kk = 0; kk < 4; ++kk) {
            short8 bfr[4];
            #pragma unroll
            for (int nt = 0; nt < 4; ++nt)
                bfr[nt] = *(const short8*)(&Bs[wn + nt * 16 + lr][kk * 32 + quad * 8]);
            #pragma unroll
            for (int mt = 0; mt < 2; ++mt)
                #pragma unroll
                for (int nt = 0; nt < 4; ++nt)
                    acc[mt][nt] = __builtin_amdgcn_mfma_f32_16x16x32_bf16(af[mt][kk], bfr[nt], acc[mt][nt], 0, 0, 0);
        }
        __syncthreads();
        #pragma unroll
        for (int nt = 0; nt < 4; ++nt) {
            const float b2v = b2[n0 + wn + nt * 16 + lr];
            #pragma unroll
            for (int mt = 0; mt < 2; ++mt) {
                #pragma unroll
                for (int r = 0; r < 4; ++r) {
                    const int row = wm + mt * 16 + quad * 4 + r;
                    msum[mt][nt][r] = fmaf(ylds[row][dcur], acc[mt][nt][r] + b2v, msum[mt][nt][r]);
                }
            }
        }
    }
    #pragma unroll
    for (int mt = 0; mt < 2; ++mt)
        #pragma unroll
        for (int r = 0; r < 4; ++r) {
            const int row = wm + mt * 16 + quad * 4 + r;
            const int dn = sidx[64 + row];
            #pragma unroll
            for (int nt = 0; nt < 4; ++nt)
                atomicAdd(&agg[(size_t)dn * 64 + nt * 16 + lr], msum[mt][nt][r]);
        }
}

// GRU v3 (r10-verified): block = 64 nodes, 4 waves split the d-loop
__global__ __launch_bounds__(256) void k4_gru(const float* __restrict__ agg,
                                              const float* __restrict__ counts,
                                              const float* __restrict__ cbias,
                                              const float* __restrict__ wpk,
                                              const float* __restrict__ b_ih,
                                              const float* __restrict__ b_hh,
                                              float* __restrict__ out) {
    const int wv = threadIdx.x >> 6;
    const int lane = threadIdx.x & 63;
    const int nb0 = blockIdx.x * 64;
    __shared__ float sM[64][65], sH[64][65];

    #pragma unroll 4
    for (int i = 0; i < 16; ++i) {
        const int r = i * 4 + wv;
        sM[r][lane] = agg[(size_t)(nb0 + r) * 64 + lane];
        sH[r][lane] = out[(size_t)(nb0 + r) * 64 + lane];
    }
    __syncthreads();
    const float rcnt = 1.0f / fmaxf(counts[nb0 + lane], 1.0f);
    float m[64], h[64];
    #pragma unroll
    for (int k = 0; k < 64; ++k) {
        m[k] = fmaxf(sM[lane][k] * rcnt + cbias[k], 0.0f);
        h[k] = sH[lane][k];
    }
    __syncthreads();

    const int d0 = wv * 16;
    #pragma unroll 1
    for (int dd = 0; dd < 16; ++dd) {
        const int d = d0 + dd;
        const float* wr = wpk + d * 384;
        float a0 = b_ih[d], a1 = b_ih[64 + d], a2 = b_ih[128 + d];
        float g0 = b_hh[d], g1 = b_hh[64 + d], g2 = b_hh[128 + d];
        #pragma unroll
        for (int k = 0; k < 64; ++k) {
            a0 = fmaf(m[k], wr[k], a0);
            a1 = fmaf(m[k], wr[64 + k], a1);
            a2 = fmaf(m[k], wr[128 + k], a2);
            g0 = fmaf(h[k], wr[192 + k], g0);
            g1 = fmaf(h[k], wr[256 + k], g1);
            g2 = fmaf(h[k], wr[320 + k], g2);
        }
        const float r_ = sigm(a0 + g0);
        const float z  = sigm(a1 + g1);
        const float nn = tanhf(a2 + r_ * g2);
        const float hd = sH[lane][d];
        sM[lane][d] = (1.0f - z) * nn + z * hd;
    }
    __syncthreads();
    #pragma unroll 4
    for (int i = 0; i < 16; ++i) {
        const int r = i * 4 + wv;
        out[(size_t)(nb0 + r) * 64 + lane] = sM[r][lane];
    }
}

// FUSED Set2Set step: LSTM (256 threads) + attention with 4-way wave-split
// online softmax and exact max/rescale merge.
__global__ __launch_bounds__(256) void k5_fused(float* __restrict__ qstar,
                                                float* __restrict__ hs, float* __restrict__ cs,
                                                const float* __restrict__ w_ih,
                                                const float* __restrict__ w_hh,
                                                const float* __restrict__ b_ih,
                                                const float* __restrict__ b_hh,
                                                const float* __restrict__ out,
                                                const int* __restrict__ rowptr) {
    const int g = blockIdx.x;
    const int j = threadIdx.x;
    __shared__ float qs[128], hv[64], gates[256], hval[64];
    __shared__ float smw[4], sSw[4], srw[4][64];
    if (j < 128) qs[j] = qstar[(size_t)g * 128 + j];
    else if (j < 192) hv[j - 128] = hs[(size_t)g * 64 + (j - 128)];
    __syncthreads();
    float acc = b_ih[j] + b_hh[j];
    for (int k4 = 0; k4 < 128; k4 += 4) {
        float4 v = *(const float4*)(w_ih + (size_t)j * 128 + k4);
        const float* pv = (const float*)&v;
        #pragma unroll
        for (int t = 0; t < 4; ++t) acc += qs[k4 + t] * pv[t];
    }
    for (int k4 = 0; k4 < 64; k4 += 4) {
        float4 v = *(const float4*)(w_hh + (size_t)j * 64 + k4);
        const float* pv = (const float*)&v;
        #pragma unroll
        for (int t = 0; t < 4; ++t) acc += hv[k4 + t] * pv[t];
    }
    gates[j] = acc;
    __syncthreads();
    if (j < 64) {
        const float ig = sigm(gates[j]);
        const float fg = sigm(gates[64 + j]);
        const float gg = tanhf(gates[128 + j]);
        const float og = sigm(gates[192 + j]);
        const float c = fg * cs[(size_t)g * 64 + j] + ig * gg;
        const float h = og * tanhf(c);
        cs[(size_t)g * 64 + j] = c;
        hs[(size_t)g * 64 + j] = h;
        qstar[(size_t)g * 128 + j] = h;
        hval[j] = h;
    }
    __syncthreads();
    // attention: wave wv handles nodes start+wv, start+wv+4, ...
    const int wv = j >> 6, lane = j & 63;
    const int start = rowptr[g], end = rowptr[g + 1];
    const float q = hval[lane];
    float m = -3.4e38f, S = 0.0f, racc = 0.0f;
    for (int n = start + wv; n < end; n += 4) {
        const float ov = out[(size_t)n * 64 + lane];
        float p = ov * q;
        #pragma unroll
        for (int off = 1; off < 64; off <<= 1) p += __shfl_xor(p, off);
        if (p > m) {
            const float sc = __expf(m - p);
            S = S * sc + 1.0f;
            racc = racc * sc + ov;
            m = p;
        } else {
            const float w = __expf(p - m);
            S += w;
            racc += w * ov;
        }
    }
    if (lane == 0) { smw[wv] = m; sSw[wv] = S; }
    srw[wv][lane] = racc;
    __syncthreads();
    if (wv == 0) {
        const float mstar = fmaxf(fmaxf(smw[0], smw[1]), fmaxf(smw[2], smw[3]));
        float Ssum = 0.0f, rsum = 0.0f;
        #pragma unroll
        for (int i = 0; i < 4; ++i) {
            const float sc = __expf(smw[i] - mstar);   // empty wave: exp(-huge)=0
            Ssum += sSw[i] * sc;
            rsum += srw[i][lane] * sc;
        }
        qstar[(size_t)g * 128 + 64 + lane] = rsum / (Ssum + 1e-16f);
    }
}

__global__ void k_out(const float* __restrict__ qstar, const float* __restrict__ outb,
                      float* __restrict__ dst, int nq, int nfeat, int out_n) {
    int i = blockIdx.x * 256 + threadIdx.x;
    if (i >= out_n) return;
    float v = 0.0f;
    if (i < nq) v = qstar[i];
    else if (i - nq < nfeat) v = outb[i - nq];
    dst[i] = v;
}

extern "C" void kernel_launch(void* const* d_in, const int* in_sizes, int n_in,
                              void* d_out, int out_size, void* d_ws, size_t ws_size,
                              hipStream_t stream) {
    constexpr int N = GN, E = GE, B = GB;

    char* ws = (char*)d_ws;
    size_t off = 0;
    auto alloc = [&](size_t bytes) { size_t o = off; off = (off + bytes + 255) & ~(size_t)255; return o; };

    int*   fl     = (int*)  (ws + alloc(19 * 4));
    int*   flagE  = (int*)  (ws + alloc(256));
    int*   flagG  = (int*)  (ws + alloc(256));
    float* counts = (float*)(ws + alloc((size_t)N * 4));
    int*   rowptr = (int*)  (ws + alloc((size_t)(B + 1) * 4));
    float* outbuf = (float*)(ws + alloc((size_t)N * 64 * 4));
    float* agg    = (float*)(ws + alloc((size_t)N * 64 * 4));
    float* qstar  = (float*)(ws + alloc((size_t)B * 128 * 4));
    float* hsb    = (float*)(ws + alloc((size_t)B * 64 * 4));
    float* csb    = (float*)(ws + alloc((size_t)B * 64 * 4));
    __hip_bfloat16* h1  = (__hip_bfloat16*)(ws + alloc((size_t)E * 128 * 2));
    __hip_bfloat16* w2T = (__hip_bfloat16*)(ws + alloc((size_t)4096 * 128 * 2));
    float* wpk    = (float*)(ws + alloc((size_t)64 * 384 * 4));

    const int fidx[15]  = {4, 5, 6, 7, 8, 9, 10, 11, 12, 13, 14, 15, 16, 17, 18};
    const int fsize[15] = {75 * 64, 64, 16 * 128, 128, 128 * 4096, 4096, 64,
                           192 * 64, 192 * 64, 192, 192, 256 * 128, 256 * 64, 256, 256};
    float* F[19] = {};
    for (int t = 0; t < 15; ++t) F[fidx[t]] = (float*)(ws + alloc((size_t)fsize[t] * 4));

    DetectArgs da;
    da.src[0] = d_in[0]; da.nhalf[0] = N * 75; da.fi[0] = 0;
    da.src[1] = d_in[1]; da.nhalf[1] = E * 16; da.fi[1] = 1;
    for (int t = 0; t < 15; ++t) { da.src[2 + t] = d_in[fidx[t]]; da.nhalf[2 + t] = fsize[t]; da.fi[2 + t] = fidx[t]; }
    k_dtype_all<<<17, 256, 0, stream>>>(da, fl);
    k_i64<<<1, 256, 0, stream>>>((const unsigned int*)d_in[2], (long long)2 * E, flagE);
    k_i64<<<1, 256, 0, stream>>>((const unsigned int*)d_in[3], (long long)N, flagG);

    CvtArgs ca;
    int pre = 0;
    for (int t = 0; t < 15; ++t) {
        ca.src[t] = d_in[fidx[t]]; ca.dst[t] = F[fidx[t]]; ca.n[t] = fsize[t]; ca.fi[t] = fidx[t];
        ca.pre[t] = pre; pre += (fsize[t] + 255) / 256;
    }
    ca.pre[15] = pre;
    k_cvt_all<<<pre, 256, 0, stream>>>(ca, fl);
    k_t2<<<4096 * 16 / 256, 256, 0, stream>>>(d_in[8], w2T, fl + 8);
    k_gpack<<<(64 * 384 + 255) / 256, 256, 0, stream>>>(F[11], F[12], wpk);

    hipMemsetAsync(counts, 0, (size_t)N * 4, stream);
    hipMemsetAsync(qstar, 0, (size_t)(B * 128 + B * 64 + B * 64) * 4, stream);

    k_counts<<<E / 256, 256, 0, stream>>>(d_in[2], flagE, counts, E);
    k_rowptr<<<(B + 1 + 255) / 256, 256, 0, stream>>>(d_in[3], flagG, rowptr, N, B);
    k_lin0<<<N / 4, 256, 0, stream>>>(d_in[0], F[4], F[5], outbuf, fl + 0);
    k1_h1<<<E / 2, 256, 0, stream>>>(d_in[1], F[6], F[7], h1, fl + 1);

    for (int it = 0; it < 3; ++it) {
        hipMemsetAsync(agg, 0, (size_t)N * 64 * 4, stream);
        k23_fused<<<E / 64, 256, 0, stream>>>(h1, w2T, F[9], outbuf, d_in[2], flagE, agg);
        k4_gru<<<N / 64, 256, 0, stream>>>(agg, counts, F[10], wpk, F[13], F[14], outbuf);
    }
    for (int t = 0; t < 3; ++t) {
        k5_fused<<<B, 256, 0, stream>>>(qstar, hsb, csb, F[15], F[16], F[17], F[18], outbuf, rowptr);
    }
    k_out<<<(out_size + 255) / 256, 256, 0, stream>>>(qstar, outbuf, (float*)d_out,
                                                      B * 128, N * 64, out_size);
}